// Round 7
// baseline (436.292 us; speedup 1.0000x reference)
//
#include <hip/hip_runtime.h>
#include <hip/hip_fp16.h>

#define RL(x) __builtin_amdgcn_readfirstlane(x)

typedef _Float16 f16x8 __attribute__((ext_vector_type(8)));
typedef _Float16 f16x4 __attribute__((ext_vector_type(4)));
typedef float    f32x16 __attribute__((ext_vector_type(16)));

// ---------------- weight prep ----------------
// w1h fp16 A-frag order: w1h[((ic*8+ky)*32 + oc)*8 + kx] = w1[oc*256 + ic*64 + ky*8 + kx] (8192 h)
// w2h fp16 MFMA-frag order: w2h[((ic*2+ot)*2+kh)*256 + ln*8 + j]
//      = w2[(ot*32+ln)*512 + ic*16 + ky*4 + kx],  k = kh*8+j, kx=k>>2, ky=k&3   (32768 halves)
// wt3n[((ic*3+ky)*8+ocg)*24 + o*3+kx] = w3[(ocg*8+o)*576 + ic*9 + ky*3 + kx]    (36864 fp32)
__global__ __launch_bounds__(256) void wprep_k(const float* __restrict__ w1,
                                               const float* __restrict__ w2,
                                               const float* __restrict__ w3,
                                               __half* __restrict__ w1h,
                                               __half* __restrict__ w2h,
                                               float* __restrict__ wt3) {
  int i = blockIdx.x * 256 + threadIdx.x;
  if (i < 8192) {
    int kx = i & 7, oc = (i >> 3) & 31, ky = (i >> 8) & 7, ic = i >> 11;
    w1h[i] = __float2half(w1[oc * 256 + ic * 64 + ky * 8 + kx]);
  }
  if (i < 32768) {
    int j = i & 7, ln = (i >> 3) & 31, kh = (i >> 8) & 1, ot = (i >> 9) & 1, ic = i >> 10;
    int k = kh * 8 + j, kx = k >> 2, ky = k & 3, oc = ot * 32 + ln;
    w2h[i] = __float2half(w2[oc * 512 + ic * 16 + ky * 4 + kx]);
  }
  if (i < 36864) {
    int o3 = i % 24, o = o3 / 3, kx = o3 - o * 3;
    int r = i / 24, ocg = r & 7, r2 = r >> 3, ky = r2 % 3, ic = r2 / 3;
    wt3[i] = w3[(ocg * 8 + o) * 576 + ic * 9 + ky * 3 + kx];
  }
}

// ---------------- conv1 (MFMA): x[1024,4,84,84] fp32 -> c1t[12800][1024] fp16 directly ----
// Per block: 2 py (rows 8q..8q+11), 32 b, all 32 oc, 20 px. 4 waves = (pyl, pxq).
// Per-ic stage [r 12][b 32][col 84] of x/256 as fp16 in LDS (64512 B, 2 blocks/CU).
// B-frag (px,t,kh) = row pyl*4+2t+kh, cols 4px..4px+7 -> two ds_read_b64.
// A-frag from w1h (16 KB, L2-hot) via per-lane global load. Writes c1t transposed
// layout directly -> t1 kernel eliminated.
__global__ __launch_bounds__(256, 2) void conv1_k(const float* __restrict__ x,
                                                  const __half* __restrict__ w1h,
                                                  const float* __restrict__ bias,
                                                  __half* __restrict__ out) {
  __shared__ __align__(16) __half xs[32256];   // [r 12][b 32][col 84]
  const int bid = blockIdx.x;        // 320 = bt*10 + q
  const int q  = bid % 10;
  const int bt = bid / 10;
  const int tid = threadIdx.x;
  const int lane = tid & 63;
  const int wv   = RL(tid >> 6);
  const int pyl = wv >> 1;           // local py 0..1
  const int pxq = wv & 1;            // px half 0..1
  const int kh = lane >> 5;
  const int ln = lane & 31;

  f32x16 acc[10];
#pragma unroll
  for (int px = 0; px < 10; ++px)
#pragma unroll
    for (int r = 0; r < 16; ++r) acc[px][r] = 0.f;

  const float inv = 1.0f / 256.0f;
  const float* xb = x + bt * 32 * 28224 + q * 8 * 84;

#pragma unroll 1
  for (int ic = 0; ic < 4; ++ic) {
    if (ic) __syncthreads();
    // ---- stage: 12 rows x 84 cols x 32 b, fp32 -> fp16/256 ----
#pragma unroll 4
    for (int pass = 0; pass < 32; ++pass) {
      int item = pass * 256 + tid;
      if (item < 8064) {               // 12*32*21
        int cg = item % 21;
        int rb = item / 21;
        int b = rb & 31, r = rb >> 5;
        const float* gp = xb + b * 28224 + ic * 7056 + r * 84 + cg * 4;
        float4 v = *(const float4*)gp;
        __half2 h01 = __floats2half2_rn(v.x * inv, v.y * inv);
        __half2 h23 = __floats2half2_rn(v.z * inv, v.w * inv);
        *(uint2*)&xs[(r * 32 + b) * 84 + cg * 4] =
            make_uint2(*(unsigned*)&h01, *(unsigned*)&h23);
      }
    }
    __syncthreads();

#pragma unroll
    for (int t = 0; t < 4; ++t) {
      f16x8 aw = *(const f16x8*)(w1h + ((ic * 8 + 2 * t + kh) * 32 + ln) * 8);
      const __half* rp = &xs[((pyl * 4 + 2 * t + kh) * 32 + ln) * 84];
#pragma unroll
      for (int px = 0; px < 10; ++px) {
        const int xg = pxq * 10 + px;
        f16x4 lo = *(const f16x4*)(rp + 4 * xg);
        f16x4 hi = *(const f16x4*)(rp + 4 * xg + 4);
        f16x8 bx;
        bx[0]=lo[0]; bx[1]=lo[1]; bx[2]=lo[2]; bx[3]=lo[3];
        bx[4]=hi[0]; bx[5]=hi[1]; bx[6]=hi[2]; bx[7]=hi[3];
        acc[px] = __builtin_amdgcn_mfma_f32_32x32x16_f16(aw, bx, acc[px], 0, 0, 0);
      }
    }
  }

  float bv[16];
#pragma unroll
  for (int r = 0; r < 16; ++r)
    bv[r] = bias[(r & 3) + 8 * (r >> 2) + 4 * kh];

  const int pyg = 2 * q + pyl;
  const int bg  = bt * 32 + ln;
#pragma unroll
  for (int px = 0; px < 10; ++px) {
    const int p = pyg * 20 + pxq * 10 + px;
#pragma unroll
    for (int r = 0; r < 16; ++r) {
      const int oc = (r & 3) + 8 * (r >> 2) + 4 * kh;
      float v = acc[px][r] + bv[r];
      out[(oc * 400 + p) * 1024 + bg] = __float2half(v > 0.f ? v : 0.f);
    }
  }
}

// ---------------- conv2 (MFMA): c1t[12800][1024] -> c2t[5184][1024], k=4, s=2 -------------
__global__ __launch_bounds__(256, 1) void conv2_k(const __half* __restrict__ in,
                                                  const __half* __restrict__ w2h,
                                                  const float* __restrict__ bias,
                                                  __half* __restrict__ out) {
  __shared__ __align__(16) __half sh[2][9216];   // per buf: slab 8192 + W 1024 halves
  const int bid = blockIdx.x;          // 144 = 9 opy * 16 bt
  const int opy = bid % 9;
  const int bt  = bid / 9;
  const int bbase = bt * 64;
  const int tid  = threadIdx.x;
  const int lane = tid & 63;
  const int wv   = RL(tid >> 6);
  const int octile = wv & 1;
  const int bsub   = wv >> 1;
  const int kh = lane >> 5;
  const int ln = lane & 31;

  const unsigned short* inu = (const unsigned short*)in;
  const unsigned short* wu  = (const unsigned short*)w2h;

  int roff[5], offA[5];
#pragma unroll
  for (int p = 0; p < 5; ++p) {
    int idx = p * 256 + tid;
    int px = idx >> 6, b = idx & 63;
    roff[p] = px * 1024 + b;
    offA[p] = b * 128 + ((((px >> 1) ^ (b & 7)) << 3) | ((px & 1) << 2));
  }
  const int base0 = (40 * opy) * 1024 + bbase;

  f32x16 acc[9];
#pragma unroll
  for (int ox = 0; ox < 9; ++ox)
#pragma unroll
    for (int r = 0; r < 16; ++r) acc[ox][r] = 0.f;

  ushort4 s0, s1, s2, s3, s4; uint2 sW;

#define C2_LOAD(icv) do {                                                     \
    const unsigned short* ibp = inu + (icv) * 409600 + base0;                 \
    s0 = make_ushort4(ibp[roff[0]], ibp[roff[0]+20480], ibp[roff[0]+40960], ibp[roff[0]+61440]); \
    s1 = make_ushort4(ibp[roff[1]], ibp[roff[1]+20480], ibp[roff[1]+40960], ibp[roff[1]+61440]); \
    s2 = make_ushort4(ibp[roff[2]], ibp[roff[2]+20480], ibp[roff[2]+40960], ibp[roff[2]+61440]); \
    s3 = make_ushort4(ibp[roff[3]], ibp[roff[3]+20480], ibp[roff[3]+40960], ibp[roff[3]+61440]); \
    s4 = make_ushort4(ibp[roff[4]], ibp[roff[4]+20480], ibp[roff[4]+40960], ibp[roff[4]+61440]); \
    sW = *(const uint2*)(wu + (icv) * 1024 + tid * 4);                        \
  } while (0)

#define C2_STORE(buf) do {                                                    \
    *(uint2*)&sh[buf][offA[0]] = make_uint2((unsigned)s0.x | ((unsigned)s0.y << 16), (unsigned)s0.z | ((unsigned)s0.w << 16)); \
    *(uint2*)&sh[buf][offA[1]] = make_uint2((unsigned)s1.x | ((unsigned)s1.y << 16), (unsigned)s1.z | ((unsigned)s1.w << 16)); \
    *(uint2*)&sh[buf][offA[2]] = make_uint2((unsigned)s2.x | ((unsigned)s2.y << 16), (unsigned)s2.z | ((unsigned)s2.w << 16)); \
    *(uint2*)&sh[buf][offA[3]] = make_uint2((unsigned)s3.x | ((unsigned)s3.y << 16), (unsigned)s3.z | ((unsigned)s3.w << 16)); \
    *(uint2*)&sh[buf][offA[4]] = make_uint2((unsigned)s4.x | ((unsigned)s4.y << 16), (unsigned)s4.z | ((unsigned)s4.w << 16)); \
    *(uint2*)&sh[buf][8192 + tid * 4] = sW;                                   \
  } while (0)

  const int offW = 8192 + octile * 512 + kh * 256 + ln * 8;
  const int bloc = bsub * 32 + ln;
  const int bx7  = bloc & 7;
  const int brow = bloc * 128;

  int cur = 0;
  C2_LOAD(0);
#pragma unroll 1
  for (int ic = 0; ic < 32; ++ic) {
    __syncthreads();
    C2_STORE(cur);
    const int icn = ic < 31 ? ic + 1 : 31;
    C2_LOAD(icn);
    __syncthreads();
    f16x8 aw = *(const f16x8*)&sh[cur][offW];
#pragma unroll
    for (int ox = 0; ox < 9; ++ox) {
      f16x8 bx = *(const f16x8*)&sh[cur][brow + (((ox + kh) ^ bx7) << 3)];
      acc[ox] = __builtin_amdgcn_mfma_f32_32x32x16_f16(aw, bx, acc[ox], 0, 0, 0);
    }
    cur ^= 1;
  }
#undef C2_LOAD
#undef C2_STORE

  float bv[16];
#pragma unroll
  for (int r = 0; r < 16; ++r)
    bv[r] = bias[octile * 32 + (r & 3) + 8 * (r >> 2) + 4 * kh];
  const int bout = bbase + bloc;
#pragma unroll
  for (int ox = 0; ox < 9; ++ox) {
#pragma unroll
    for (int r = 0; r < 16; ++r) {
      const int oc = octile * 32 + (r & 3) + 8 * (r >> 2) + 4 * kh;
      float v = acc[ox][r] + bv[r];
      out[(oc * 81 + opy * 9 + ox) * 1024 + bout] = __float2half(v > 0.f ? v : 0.f);
    }
  }
}

// ---------------- conv3: c2t[5184][1024] -> c3t[3136][1024], k=3, s=1 (fp16 io) ----------
__global__ __launch_bounds__(128, 2) void conv3_k(const __half* __restrict__ in,
                                                  const float* __restrict__ wt,   // wt3n
                                                  const float* __restrict__ bias,
                                                  __half* __restrict__ out) {
  const int bid = blockIdx.x;            // 1792 = 128*(grp>>3) + 8*ocg + (grp&7)
  const int ocg = (bid >> 3) & 15;
  const int grp = ((bid >> 7) << 3) | (bid & 7);
  const int opy = grp % 7;
  const int bg  = grp / 7;
  const int tid  = threadIdx.x;
  const int lane = tid & 63;
  const int wv   = RL(tid >> 6);

  float acc[4][7];
#pragma unroll
  for (int o = 0; o < 4; ++o)
#pragma unroll
    for (int ox = 0; ox < 7; ++ox) acc[o][ox] = 0.f;

  const __half* ib = in + bg * 64 + lane;
  const int ic0 = wv * 32;

#pragma unroll 1
  for (int ici = 0; ici < 32; ++ici) {
    const int ic = ic0 + ici;
#pragma unroll
    for (int ky = 0; ky < 3; ++ky) {
      const float* wp = wt + ((ic * 3 + ky) * 8 + (ocg >> 1)) * 24 + (ocg & 1) * 12;
      float wk[12];
#pragma unroll
      for (int q = 0; q < 12; ++q) wk[q] = wp[q];
      const __half* rp = ib + (ic * 81 + (opy + ky) * 9) * 1024;
      float iv[9];
#pragma unroll
      for (int q = 0; q < 9; ++q) iv[q] = __half2float(rp[q * 1024]);
#pragma unroll
      for (int o = 0; o < 4; ++o)
#pragma unroll
        for (int ox = 0; ox < 7; ++ox)
#pragma unroll
          for (int kx = 0; kx < 3; ++kx)
            acc[o][ox] = fmaf(iv[ox + kx], wk[o * 3 + kx], acc[o][ox]);
    }
  }

  __shared__ float red[4][7][64];
  if (wv == 1) {
#pragma unroll
    for (int o = 0; o < 4; ++o)
#pragma unroll
      for (int ox = 0; ox < 7; ++ox) red[o][ox][lane] = acc[o][ox];
  }
  __syncthreads();
  if (wv == 0) {
#pragma unroll
    for (int o = 0; o < 4; ++o) {
      const int oc = ocg * 4 + o;
      const float bj = bias[oc];
#pragma unroll
      for (int ox = 0; ox < 7; ++ox) {
        float v = acc[o][ox] + red[o][ox][lane] + bj;
        out[(oc * 49 + opy * 7 + ox) * 1024 + bg * 64 + lane] =
            __float2half(v > 0.f ? v : 0.f);
      }
    }
  }
}

// ---------------- fc1a: c3t[3136][1024] @ fw1[3136][256] -> part[16][256][1024] -----------
__global__ __launch_bounds__(64, 2) void fc1a_k(const __half* __restrict__ a,
                                                const float* __restrict__ w,
                                                float* __restrict__ part) {
  const int bid = blockIdx.x;            // 4096 = 128*(grp>>3) + 8*jg + (grp&7)
  const int jg  = (bid >> 3) & 15;
  const int grp = ((bid >> 7) << 3) | (bid & 7);
  const int kc  = grp & 15;
  const int bg  = grp >> 4;
  const int lane = threadIdx.x;

  float acc[16];
#pragma unroll
  for (int j = 0; j < 16; ++j) acc[j] = 0.f;

  const __half* ap = a + kc * 196 * 1024 + bg * 64 + lane;
  const float* wp0 = w + kc * 196 * 256 + jg * 16;

#pragma unroll 4
  for (int k = 0; k < 196; ++k) {
    float av = __half2float(ap[k * 1024]);
    const float* wp = wp0 + k * 256;
#pragma unroll
    for (int j = 0; j < 16; ++j) acc[j] = fmaf(av, wp[j], acc[j]);
  }
#pragma unroll
  for (int j = 0; j < 16; ++j)
    part[(kc * 256 + jg * 16 + j) * 1024 + bg * 64 + lane] = acc[j];
}

// ---------------- fc1b: reduce 16 partials + bias + relu -> h_t[256][1024] ----------------
__global__ __launch_bounds__(256) void fc1b_k(const float* __restrict__ part,
                                              const float* __restrict__ bias,
                                              float* __restrict__ h) {
  int idx = blockIdx.x * 256 + threadIdx.x;   // j*1024 + b
  float s = bias[idx >> 10];
#pragma unroll
  for (int c = 0; c < 16; ++c) s += part[c * 262144 + idx];
  h[idx] = s > 0.f ? s : 0.f;
}

// ---------------- fc2 + softmax + dist/res (reads h_t[k][b]) ----------------
__global__ __launch_bounds__(256) void fc2_k(const float* __restrict__ h,     // [256][1024]
                                             const float* __restrict__ w,     // [256][51]
                                             const float* __restrict__ bias,
                                             const float* __restrict__ z,
                                             float* __restrict__ dist,        // [1024][6][51]
                                             float* __restrict__ res) {       // [1024][6]
  __shared__ float wl[256 * 51];
  const int tid = threadIdx.x;
#pragma unroll
  for (int i = tid; i < 256 * 51; i += 256) wl[i] = w[i];
  __syncthreads();

  const int j   = tid & 63;
  const int b   = blockIdx.x * 4 + RL(tid >> 6);
  const int jc = j < 51 ? j : 50;
  float acc = bias[jc];
#pragma unroll 8
  for (int k = 0; k < 256; ++k)
    acc = fmaf(h[k * 1024 + b], wl[k * 51 + jc], acc);
  float logit = (j < 51) ? acc : -1e30f;
  float m = logit;
#pragma unroll
  for (int o = 32; o > 0; o >>= 1) m = fmaxf(m, __shfl_xor(m, o, 64));
  float e = (j < 51) ? __expf(logit - m) : 0.f;
  float ssum = e;
#pragma unroll
  for (int o = 32; o > 0; o >>= 1) ssum += __shfl_xor(ssum, o, 64);
  float p = e / ssum;
  float zv = (j < 51) ? z[jc] : 0.f;
  float rz = p * zv;
#pragma unroll
  for (int o = 32; o > 0; o >>= 1) rz += __shfl_xor(rz, o, 64);
  if (j < 51) {
    float* db = dist + b * 6 * 51 + j;
#pragma unroll
    for (int n = 0; n < 6; ++n) db[n * 51] = p;
  }
  if (j < 6) res[b * 6 + j] = rz;
}

extern "C" void kernel_launch(void* const* d_in, const int* in_sizes, int n_in,
                              void* d_out, int out_size, void* d_ws, size_t ws_size,
                              hipStream_t stream) {
  const float* x   = (const float*)d_in[0];
  const float* cw1 = (const float*)d_in[1];
  const float* cb1 = (const float*)d_in[2];
  const float* cw2 = (const float*)d_in[3];
  const float* cb2 = (const float*)d_in[4];
  const float* cw3 = (const float*)d_in[5];
  const float* cb3 = (const float*)d_in[6];
  const float* fw1 = (const float*)d_in[7];
  const float* fb1 = (const float*)d_in[8];
  const float* fw2 = (const float*)d_in[9];
  const float* fb2 = (const float*)d_in[10];
  const float* z   = (const float*)d_in[11];

  float* ws = (float*)d_ws;
  // float-offsets (fp16 buffers occupy half):
  // c1t : [6553600, 13107200)   12800*1024 halfs (conv1 writes transposed directly)
  // c2t : [13107200, 15761408)  5184*1024 halfs
  // c3t : [15761408, 17367040)  3136*1024 halfs
  // part: [0, 4194304)          16*256*1024 fp32
  // h_t : [4194304, 4456448)    256*1024 fp32
  __half* c1t = (__half*)(ws + 6553600);
  __half* c2t = (__half*)(ws + 13107200);
  __half* c3t = (__half*)(ws + 15761408);
  float*  pw  = ws;
  float*  h_t = ws + 4194304;

  // Weight scratch in d_out (floats): wt3n [0,36864), w1h halves [36864,40960),
  // w2h halves [45056,61440). dist written last (fc2).
  float*  wt3n = (float*)d_out;
  __half* w1h  = (__half*)((float*)d_out + 36864);
  __half* w2h  = (__half*)((float*)d_out + 45056);

  float* dist = (float*)d_out;
  float* res  = dist + 1024 * 6 * 51;

  wprep_k<<<144, 256, 0, stream>>>(cw1, cw2, cw3, w1h, w2h, wt3n);
  conv1_k<<<320, 256, 0, stream>>>(x, w1h, cb1, c1t);
  conv2_k<<<144, 256, 0, stream>>>(c1t, w2h, cb2, c2t);
  conv3_k<<<1792, 128, 0, stream>>>(c2t, wt3n, cb3, c3t);
  fc1a_k<<<4096, 64, 0, stream>>>(c3t, fw1, pw);
  fc1b_k<<<1024, 256, 0, stream>>>(pw, fb1, h_t);
  fc2_k<<<256, 256, 0, stream>>>(h_t, fw2, fb2, z, dist, res);
}

// Round 8
// 428.543 us; speedup vs baseline: 1.0181x; 1.0181x over previous
//
#include <hip/hip_runtime.h>
#include <hip/hip_fp16.h>

#define RL(x) __builtin_amdgcn_readfirstlane(x)

typedef _Float16 f16x8 __attribute__((ext_vector_type(8)));
typedef float    f32x16 __attribute__((ext_vector_type(16)));

// ---------------- weight prep ----------------
// w1h fp16 A-frag order, PRE-SCALED by 1/256 (x/256 folded into weights):
//   w1h[((ic*8+ky)*32 + oc)*8 + kx] = w1[oc*256 + ic*64 + ky*8 + kx] / 256      (8192 h)
// w2h fp16 MFMA-frag order: w2h[((ic*2+ot)*2+kh)*256 + ln*8 + j]
//      = w2[(ot*32+ln)*512 + ic*16 + ky*4 + kx],  k = kh*8+j, kx=k>>2, ky=k&3   (32768 halves)
// wt3n[((ic*3+ky)*8+ocg)*24 + o*3+kx] = w3[(ocg*8+o)*576 + ic*9 + ky*3 + kx]    (36864 fp32)
__global__ __launch_bounds__(256) void wprep_k(const float* __restrict__ w1,
                                               const float* __restrict__ w2,
                                               const float* __restrict__ w3,
                                               __half* __restrict__ w1h,
                                               __half* __restrict__ w2h,
                                               float* __restrict__ wt3) {
  int i = blockIdx.x * 256 + threadIdx.x;
  if (i < 8192) {
    int kx = i & 7, oc = (i >> 3) & 31, ky = (i >> 8) & 7, ic = i >> 11;
    w1h[i] = __float2half(w1[oc * 256 + ic * 64 + ky * 8 + kx] * 0.00390625f);
  }
  if (i < 32768) {
    int j = i & 7, ln = (i >> 3) & 31, kh = (i >> 8) & 1, ot = (i >> 9) & 1, ic = i >> 10;
    int k = kh * 8 + j, kx = k >> 2, ky = k & 3, oc = ot * 32 + ln;
    w2h[i] = __float2half(w2[oc * 512 + ic * 16 + ky * 4 + kx]);
  }
  if (i < 36864) {
    int o3 = i % 24, o = o3 / 3, kx = o3 - o * 3;
    int r = i / 24, ocg = r & 7, r2 = r >> 3, ky = r2 % 3, ic = r2 / 3;
    wt3[i] = w3[(ocg * 8 + o) * 576 + ic * 9 + ky * 3 + kx];
  }
}

// ---------------- conv1 (MFMA, no LDS): x[1024,4,84,84] fp32 -> c1t[12800][1024] fp16 -----
// Per block: 2 py, 32 b, 32 oc, 20 px; 4 waves = (pyl, pxq); grid 320.
// B-frags loaded per-lane DIRECTLY from global x (two float4, L1/L2/L3-served; x fits L3),
// converted via cvt_pkrtz; scale 1/256 folded into w1h. No LDS, no barriers.
__global__ __launch_bounds__(256, 2) void conv1_k(const float* __restrict__ x,
                                                  const __half* __restrict__ w1h,
                                                  const float* __restrict__ bias,
                                                  __half* __restrict__ out) {
  const int bid = blockIdx.x;        // 320 = bt*10 + q
  const int q  = bid % 10;
  const int bt = bid / 10;
  const int tid = threadIdx.x;
  const int lane = tid & 63;
  const int wv   = RL(tid >> 6);
  const int pyl = wv >> 1;           // local py 0..1
  const int pxq = wv & 1;            // px half 0..1
  const int kh = lane >> 5;
  const int ln = lane & 31;

  f32x16 acc[10];
#pragma unroll
  for (int px = 0; px < 10; ++px)
#pragma unroll
    for (int r = 0; r < 16; ++r) acc[px][r] = 0.f;

  // per-lane input base: batch bt*32+ln, row q*8 + pyl*4 + kh (+2t), col 4*xg (+pxq*40)
  const float* xb = x + (bt * 32 + ln) * 28224 + (q * 8 + pyl * 4 + kh) * 84 + pxq * 40;

#pragma unroll 1
  for (int ic = 0; ic < 4; ++ic) {
#pragma unroll
    for (int t = 0; t < 4; ++t) {
      f16x8 aw = *(const f16x8*)(w1h + ((ic * 8 + 2 * t + kh) * 32 + ln) * 8);
      const float* rp = xb + ic * 7056 + 2 * t * 84;
#pragma unroll
      for (int px = 0; px < 10; ++px) {
        float4 lo = *(const float4*)(rp + 4 * px);
        float4 hi = *(const float4*)(rp + 4 * px + 4);
        __half2 p0 = __floats2half2_rn(lo.x, lo.y);
        __half2 p1 = __floats2half2_rn(lo.z, lo.w);
        __half2 p2 = __floats2half2_rn(hi.x, hi.y);
        __half2 p3 = __floats2half2_rn(hi.z, hi.w);
        uint4 u = make_uint4(*(unsigned*)&p0, *(unsigned*)&p1,
                             *(unsigned*)&p2, *(unsigned*)&p3);
        f16x8 bx = *(f16x8*)&u;
        acc[px] = __builtin_amdgcn_mfma_f32_32x32x16_f16(aw, bx, acc[px], 0, 0, 0);
      }
    }
  }

  float bv[16];
#pragma unroll
  for (int r = 0; r < 16; ++r)
    bv[r] = bias[(r & 3) + 8 * (r >> 2) + 4 * kh];

  const int pyg = 2 * q + pyl;
  const int bg  = bt * 32 + ln;
#pragma unroll
  for (int px = 0; px < 10; ++px) {
    const int p = pyg * 20 + pxq * 10 + px;
#pragma unroll
    for (int r = 0; r < 16; ++r) {
      const int oc = (r & 3) + 8 * (r >> 2) + 4 * kh;
      float v = acc[px][r] + bv[r];
      out[(oc * 400 + p) * 1024 + bg] = __float2half(v > 0.f ? v : 0.f);
    }
  }
}

// ---------------- conv2 (MFMA): c1t[12800][1024] -> c2t[5184][1024], k=4, s=2 -------------
__global__ __launch_bounds__(256, 1) void conv2_k(const __half* __restrict__ in,
                                                  const __half* __restrict__ w2h,
                                                  const float* __restrict__ bias,
                                                  __half* __restrict__ out) {
  __shared__ __align__(16) __half sh[2][9216];   // per buf: slab 8192 + W 1024 halves
  const int bid = blockIdx.x;          // 144 = 9 opy * 16 bt
  const int opy = bid % 9;
  const int bt  = bid / 9;
  const int bbase = bt * 64;
  const int tid  = threadIdx.x;
  const int lane = tid & 63;
  const int wv   = RL(tid >> 6);
  const int octile = wv & 1;
  const int bsub   = wv >> 1;
  const int kh = lane >> 5;
  const int ln = lane & 31;

  const unsigned short* inu = (const unsigned short*)in;
  const unsigned short* wu  = (const unsigned short*)w2h;

  int roff[5], offA[5];
#pragma unroll
  for (int p = 0; p < 5; ++p) {
    int idx = p * 256 + tid;
    int px = idx >> 6, b = idx & 63;
    roff[p] = px * 1024 + b;
    offA[p] = b * 128 + ((((px >> 1) ^ (b & 7)) << 3) | ((px & 1) << 2));
  }
  const int base0 = (40 * opy) * 1024 + bbase;

  f32x16 acc[9];
#pragma unroll
  for (int ox = 0; ox < 9; ++ox)
#pragma unroll
    for (int r = 0; r < 16; ++r) acc[ox][r] = 0.f;

  ushort4 s0, s1, s2, s3, s4; uint2 sW;

#define C2_LOAD(icv) do {                                                     \
    const unsigned short* ibp = inu + (icv) * 409600 + base0;                 \
    s0 = make_ushort4(ibp[roff[0]], ibp[roff[0]+20480], ibp[roff[0]+40960], ibp[roff[0]+61440]); \
    s1 = make_ushort4(ibp[roff[1]], ibp[roff[1]+20480], ibp[roff[1]+40960], ibp[roff[1]+61440]); \
    s2 = make_ushort4(ibp[roff[2]], ibp[roff[2]+20480], ibp[roff[2]+40960], ibp[roff[2]+61440]); \
    s3 = make_ushort4(ibp[roff[3]], ibp[roff[3]+20480], ibp[roff[3]+40960], ibp[roff[3]+61440]); \
    s4 = make_ushort4(ibp[roff[4]], ibp[roff[4]+20480], ibp[roff[4]+40960], ibp[roff[4]+61440]); \
    sW = *(const uint2*)(wu + (icv) * 1024 + tid * 4);                        \
  } while (0)

#define C2_STORE(buf) do {                                                    \
    *(uint2*)&sh[buf][offA[0]] = make_uint2((unsigned)s0.x | ((unsigned)s0.y << 16), (unsigned)s0.z | ((unsigned)s0.w << 16)); \
    *(uint2*)&sh[buf][offA[1]] = make_uint2((unsigned)s1.x | ((unsigned)s1.y << 16), (unsigned)s1.z | ((unsigned)s1.w << 16)); \
    *(uint2*)&sh[buf][offA[2]] = make_uint2((unsigned)s2.x | ((unsigned)s2.y << 16), (unsigned)s2.z | ((unsigned)s2.w << 16)); \
    *(uint2*)&sh[buf][offA[3]] = make_uint2((unsigned)s3.x | ((unsigned)s3.y << 16), (unsigned)s3.z | ((unsigned)s3.w << 16)); \
    *(uint2*)&sh[buf][offA[4]] = make_uint2((unsigned)s4.x | ((unsigned)s4.y << 16), (unsigned)s4.z | ((unsigned)s4.w << 16)); \
    *(uint2*)&sh[buf][8192 + tid * 4] = sW;                                   \
  } while (0)

  const int offW = 8192 + octile * 512 + kh * 256 + ln * 8;
  const int bloc = bsub * 32 + ln;
  const int bx7  = bloc & 7;
  const int brow = bloc * 128;

  int cur = 0;
  C2_LOAD(0);
#pragma unroll 1
  for (int ic = 0; ic < 32; ++ic) {
    __syncthreads();
    C2_STORE(cur);
    const int icn = ic < 31 ? ic + 1 : 31;
    C2_LOAD(icn);
    __syncthreads();
    f16x8 aw = *(const f16x8*)&sh[cur][offW];
#pragma unroll
    for (int ox = 0; ox < 9; ++ox) {
      f16x8 bx = *(const f16x8*)&sh[cur][brow + (((ox + kh) ^ bx7) << 3)];
      acc[ox] = __builtin_amdgcn_mfma_f32_32x32x16_f16(aw, bx, acc[ox], 0, 0, 0);
    }
    cur ^= 1;
  }
#undef C2_LOAD
#undef C2_STORE

  float bv[16];
#pragma unroll
  for (int r = 0; r < 16; ++r)
    bv[r] = bias[octile * 32 + (r & 3) + 8 * (r >> 2) + 4 * kh];
  const int bout = bbase + bloc;
#pragma unroll
  for (int ox = 0; ox < 9; ++ox) {
#pragma unroll
    for (int r = 0; r < 16; ++r) {
      const int oc = octile * 32 + (r & 3) + 8 * (r >> 2) + 4 * kh;
      float v = acc[ox][r] + bv[r];
      out[(oc * 81 + opy * 9 + ox) * 1024 + bout] = __float2half(v > 0.f ? v : 0.f);
    }
  }
}

// ---------------- conv3: c2t[5184][1024] -> c3t[3136][1024], k=3, s=1 (fp16 io) ----------
__global__ __launch_bounds__(128, 2) void conv3_k(const __half* __restrict__ in,
                                                  const float* __restrict__ wt,   // wt3n
                                                  const float* __restrict__ bias,
                                                  __half* __restrict__ out) {
  const int bid = blockIdx.x;            // 1792 = 128*(grp>>3) + 8*ocg + (grp&7)
  const int ocg = (bid >> 3) & 15;
  const int grp = ((bid >> 7) << 3) | (bid & 7);
  const int opy = grp % 7;
  const int bg  = grp / 7;
  const int tid  = threadIdx.x;
  const int lane = tid & 63;
  const int wv   = RL(tid >> 6);

  float acc[4][7];
#pragma unroll
  for (int o = 0; o < 4; ++o)
#pragma unroll
    for (int ox = 0; ox < 7; ++ox) acc[o][ox] = 0.f;

  const __half* ib = in + bg * 64 + lane;
  const int ic0 = wv * 32;

#pragma unroll 1
  for (int ici = 0; ici < 32; ++ici) {
    const int ic = ic0 + ici;
#pragma unroll
    for (int ky = 0; ky < 3; ++ky) {
      const float* wp = wt + ((ic * 3 + ky) * 8 + (ocg >> 1)) * 24 + (ocg & 1) * 12;
      float wk[12];
#pragma unroll
      for (int q = 0; q < 12; ++q) wk[q] = wp[q];
      const __half* rp = ib + (ic * 81 + (opy + ky) * 9) * 1024;
      float iv[9];
#pragma unroll
      for (int q = 0; q < 9; ++q) iv[q] = __half2float(rp[q * 1024]);
#pragma unroll
      for (int o = 0; o < 4; ++o)
#pragma unroll
        for (int ox = 0; ox < 7; ++ox)
#pragma unroll
          for (int kx = 0; kx < 3; ++kx)
            acc[o][ox] = fmaf(iv[ox + kx], wk[o * 3 + kx], acc[o][ox]);
    }
  }

  __shared__ float red[4][7][64];
  if (wv == 1) {
#pragma unroll
    for (int o = 0; o < 4; ++o)
#pragma unroll
      for (int ox = 0; ox < 7; ++ox) red[o][ox][lane] = acc[o][ox];
  }
  __syncthreads();
  if (wv == 0) {
#pragma unroll
    for (int o = 0; o < 4; ++o) {
      const int oc = ocg * 4 + o;
      const float bj = bias[oc];
#pragma unroll
      for (int ox = 0; ox < 7; ++ox) {
        float v = acc[o][ox] + red[o][ox][lane] + bj;
        out[(oc * 49 + opy * 7 + ox) * 1024 + bg * 64 + lane] =
            __float2half(v > 0.f ? v : 0.f);
      }
    }
  }
}

// ---------------- fc1a: c3t[3136][1024] @ fw1[3136][256] -> part[16][256][1024] -----------
__global__ __launch_bounds__(64, 2) void fc1a_k(const __half* __restrict__ a,
                                                const float* __restrict__ w,
                                                float* __restrict__ part) {
  const int bid = blockIdx.x;            // 4096 = 128*(grp>>3) + 8*jg + (grp&7)
  const int jg  = (bid >> 3) & 15;
  const int grp = ((bid >> 7) << 3) | (bid & 7);
  const int kc  = grp & 15;
  const int bg  = grp >> 4;
  const int lane = threadIdx.x;

  float acc[16];
#pragma unroll
  for (int j = 0; j < 16; ++j) acc[j] = 0.f;

  const __half* ap = a + kc * 196 * 1024 + bg * 64 + lane;
  const float* wp0 = w + kc * 196 * 256 + jg * 16;

#pragma unroll 4
  for (int k = 0; k < 196; ++k) {
    float av = __half2float(ap[k * 1024]);
    const float* wp = wp0 + k * 256;
#pragma unroll
    for (int j = 0; j < 16; ++j) acc[j] = fmaf(av, wp[j], acc[j]);
  }
#pragma unroll
  for (int j = 0; j < 16; ++j)
    part[(kc * 256 + jg * 16 + j) * 1024 + bg * 64 + lane] = acc[j];
}

// ---------------- fc1b: reduce 16 partials + bias + relu -> h_t[256][1024] ----------------
__global__ __launch_bounds__(256) void fc1b_k(const float* __restrict__ part,
                                              const float* __restrict__ bias,
                                              float* __restrict__ h) {
  int idx = blockIdx.x * 256 + threadIdx.x;   // j*1024 + b
  float s = bias[idx >> 10];
#pragma unroll
  for (int c = 0; c < 16; ++c) s += part[c * 262144 + idx];
  h[idx] = s > 0.f ? s : 0.f;
}

// ---------------- fc2 + softmax + dist/res (reads h_t[k][b]) ----------------
__global__ __launch_bounds__(256) void fc2_k(const float* __restrict__ h,     // [256][1024]
                                             const float* __restrict__ w,     // [256][51]
                                             const float* __restrict__ bias,
                                             const float* __restrict__ z,
                                             float* __restrict__ dist,        // [1024][6][51]
                                             float* __restrict__ res) {       // [1024][6]
  __shared__ float wl[256 * 51];
  const int tid = threadIdx.x;
#pragma unroll
  for (int i = tid; i < 256 * 51; i += 256) wl[i] = w[i];
  __syncthreads();

  const int j   = tid & 63;
  const int b   = blockIdx.x * 4 + RL(tid >> 6);
  const int jc = j < 51 ? j : 50;
  float acc = bias[jc];
#pragma unroll 8
  for (int k = 0; k < 256; ++k)
    acc = fmaf(h[k * 1024 + b], wl[k * 51 + jc], acc);
  float logit = (j < 51) ? acc : -1e30f;
  float m = logit;
#pragma unroll
  for (int o = 32; o > 0; o >>= 1) m = fmaxf(m, __shfl_xor(m, o, 64));
  float e = (j < 51) ? __expf(logit - m) : 0.f;
  float ssum = e;
#pragma unroll
  for (int o = 32; o > 0; o >>= 1) ssum += __shfl_xor(ssum, o, 64);
  float p = e / ssum;
  float zv = (j < 51) ? z[jc] : 0.f;
  float rz = p * zv;
#pragma unroll
  for (int o = 32; o > 0; o >>= 1) rz += __shfl_xor(rz, o, 64);
  if (j < 51) {
    float* db = dist + b * 6 * 51 + j;
#pragma unroll
    for (int n = 0; n < 6; ++n) db[n * 51] = p;
  }
  if (j < 6) res[b * 6 + j] = rz;
}

extern "C" void kernel_launch(void* const* d_in, const int* in_sizes, int n_in,
                              void* d_out, int out_size, void* d_ws, size_t ws_size,
                              hipStream_t stream) {
  const float* x   = (const float*)d_in[0];
  const float* cw1 = (const float*)d_in[1];
  const float* cb1 = (const float*)d_in[2];
  const float* cw2 = (const float*)d_in[3];
  const float* cb2 = (const float*)d_in[4];
  const float* cw3 = (const float*)d_in[5];
  const float* cb3 = (const float*)d_in[6];
  const float* fw1 = (const float*)d_in[7];
  const float* fb1 = (const float*)d_in[8];
  const float* fw2 = (const float*)d_in[9];
  const float* fb2 = (const float*)d_in[10];
  const float* z   = (const float*)d_in[11];

  float* ws = (float*)d_ws;
  // float-offsets (fp16 buffers occupy half):
  // c1t : [6553600, 13107200)   12800*1024 halfs (conv1 writes transposed directly)
  // c2t : [13107200, 15761408)  5184*1024 halfs
  // c3t : [15761408, 17367040)  3136*1024 halfs
  // part: [0, 4194304)          16*256*1024 fp32
  // h_t : [4194304, 4456448)    256*1024 fp32
  __half* c1t = (__half*)(ws + 6553600);
  __half* c2t = (__half*)(ws + 13107200);
  __half* c3t = (__half*)(ws + 15761408);
  float*  pw  = ws;
  float*  h_t = ws + 4194304;

  // Weight scratch in d_out (floats): wt3n [0,36864), w1h halves [36864,40960),
  // w2h halves [45056,61440). dist written last (fc2).
  float*  wt3n = (float*)d_out;
  __half* w1h  = (__half*)((float*)d_out + 36864);
  __half* w2h  = (__half*)((float*)d_out + 45056);

  float* dist = (float*)d_out;
  float* res  = dist + 1024 * 6 * 51;

  wprep_k<<<144, 256, 0, stream>>>(cw1, cw2, cw3, w1h, w2h, wt3n);
  conv1_k<<<320, 256, 0, stream>>>(x, w1h, cb1, c1t);
  conv2_k<<<144, 256, 0, stream>>>(c1t, w2h, cb2, c2t);
  conv3_k<<<1792, 128, 0, stream>>>(c2t, wt3n, cb3, c3t);
  fc1a_k<<<4096, 64, 0, stream>>>(c3t, fw1, pw);
  fc1b_k<<<1024, 256, 0, stream>>>(pw, fb1, h_t);
  fc2_k<<<256, 256, 0, stream>>>(h_t, fw2, fb2, z, dist, res);
}

// Round 9
// 395.442 us; speedup vs baseline: 1.1033x; 1.0837x over previous
//
#include <hip/hip_runtime.h>
#include <hip/hip_fp16.h>

#define RL(x) __builtin_amdgcn_readfirstlane(x)

typedef _Float16 f16x8 __attribute__((ext_vector_type(8)));
typedef float    f32x16 __attribute__((ext_vector_type(16)));

// ---------------- weight prep ----------------
// w1h fp16 A-frag order, PRE-SCALED by 1/256 (x/256 folded into weights):
//   w1h[((ic*8+ky)*32 + oc)*8 + kx] = w1[oc*256 + ic*64 + ky*8 + kx] / 256      (8192 h)
// w2h fp16 MFMA-frag order: w2h[((ic*2+ot)*2+kh)*256 + ln*8 + j]
//      = w2[(ot*32+ln)*512 + ic*16 + ky*4 + kx],  k = kh*8+j, kx=k>>2, ky=k&3   (32768 halves)
// wt3n[((ic*3+ky)*8+ocg)*24 + o*3+kx] = w3[(ocg*8+o)*576 + ic*9 + ky*3 + kx]    (36864 fp32)
__global__ __launch_bounds__(256) void wprep_k(const float* __restrict__ w1,
                                               const float* __restrict__ w2,
                                               const float* __restrict__ w3,
                                               __half* __restrict__ w1h,
                                               __half* __restrict__ w2h,
                                               float* __restrict__ wt3) {
  int i = blockIdx.x * 256 + threadIdx.x;
  if (i < 8192) {
    int kx = i & 7, oc = (i >> 3) & 31, ky = (i >> 8) & 7, ic = i >> 11;
    w1h[i] = __float2half(w1[oc * 256 + ic * 64 + ky * 8 + kx] * 0.00390625f);
  }
  if (i < 32768) {
    int j = i & 7, ln = (i >> 3) & 31, kh = (i >> 8) & 1, ot = (i >> 9) & 1, ic = i >> 10;
    int k = kh * 8 + j, kx = k >> 2, ky = k & 3, oc = ot * 32 + ln;
    w2h[i] = __float2half(w2[oc * 512 + ic * 16 + ky * 4 + kx]);
  }
  if (i < 36864) {
    int o3 = i % 24, o = o3 / 3, kx = o3 - o * 3;
    int r = i / 24, ocg = r & 7, r2 = r >> 3, ky = r2 % 3, ic = r2 / 3;
    wt3[i] = w3[(ocg * 8 + o) * 576 + ic * 9 + ky * 3 + kx];
  }
}

// ---------------- conv1 (MFMA, pixels-on-lanes): x[1024,4,84,84] -> c1h[b][32*400] fp16 ---
// One block per image b. GEMM C[32 oc][400 p] = W[32][256] @ im2col. MFMA cols = pixels:
// lane ln = pixel within tile, so frag j=kx reads 8 CONSECUTIVE floats of the L1-resident
// 28 KB ic-plane (16B-aligned float4 pair). x read exactly once per image. Wave w owns
// ptiles {w, w+4, w+8} (+{12} for w==0). Output c1h batch-major (coalesced); t1 transposes.
__global__ __launch_bounds__(256, 2) void conv1_k(const float* __restrict__ x,
                                                  const __half* __restrict__ w1h,
                                                  const float* __restrict__ bias,
                                                  __half* __restrict__ out) {
  const int b = blockIdx.x;
  const int tid = threadIdx.x;
  const int lane = tid & 63;
  const int wv   = RL(tid >> 6);
  const int kh = lane >> 5;
  const int ln = lane & 31;
  const int nt = (wv == 0) ? 4 : 3;

  int ibs[4], pvv[4];
#pragma unroll
  for (int tt = 0; tt < 4; ++tt) {
    int p = (wv + tt * 4) * 32 + ln;
    pvv[tt] = (p < 400);
    if (p > 399) p = 399;
    int py = p / 20, px = p - py * 20;
    ibs[tt] = py * 336 + px * 4;       // float offset of (4py, 4px) in an 84x84 plane
  }

  f32x16 acc[4];
#pragma unroll
  for (int tt = 0; tt < 4; ++tt)
#pragma unroll
    for (int r = 0; r < 16; ++r) acc[tt][r] = 0.f;

  const float* xb = x + b * 28224;

#pragma unroll 1
  for (int ic = 0; ic < 4; ++ic) {
#pragma unroll
    for (int t = 0; t < 4; ++t) {
      f16x8 aw = *(const f16x8*)(w1h + ((ic * 8 + 2 * t + kh) * 32 + ln) * 8);
      const float* rp = xb + ic * 7056 + (2 * t + kh) * 84;
#pragma unroll
      for (int tt = 0; tt < 4; ++tt) {
        if (tt < nt) {
          const float* ap = rp + ibs[tt];
          float4 lo = *(const float4*)ap;
          float4 hi = *(const float4*)(ap + 4);
          __half2 p0 = __floats2half2_rn(lo.x, lo.y);
          __half2 p1 = __floats2half2_rn(lo.z, lo.w);
          __half2 p2 = __floats2half2_rn(hi.x, hi.y);
          __half2 p3 = __floats2half2_rn(hi.z, hi.w);
          uint4 u = make_uint4(*(unsigned*)&p0, *(unsigned*)&p1,
                               *(unsigned*)&p2, *(unsigned*)&p3);
          f16x8 bx = *(f16x8*)&u;
          acc[tt] = __builtin_amdgcn_mfma_f32_32x32x16_f16(aw, bx, acc[tt], 0, 0, 0);
        }
      }
    }
  }

  float bv[16];
#pragma unroll
  for (int r = 0; r < 16; ++r)
    bv[r] = bias[(r & 3) + 8 * (r >> 2) + 4 * kh];

#pragma unroll
  for (int tt = 0; tt < 4; ++tt) {
    if (tt < nt && pvv[tt]) {
      const int p = (wv + tt * 4) * 32 + ln;
#pragma unroll
      for (int r = 0; r < 16; ++r) {
        const int oc = (r & 3) + 8 * (r >> 2) + 4 * kh;
        float v = acc[tt][r] + bv[r];
        out[b * 12800 + oc * 400 + p] = __float2half(v > 0.f ? v : 0.f);
      }
    }
  }
}

// ---------------- t1: transpose c1h[1024][12800] -> c1t[12800][1024] (fp16) ----------------
__global__ __launch_bounds__(256) void t1_k(const __half* __restrict__ in,
                                            __half* __restrict__ out) {
  __shared__ __half t[64][65];
  const int kb = blockIdx.x * 64;   // 200 tiles
  const int bb = blockIdx.y * 64;   // 16 tiles
  const int lane = threadIdx.x & 63;
  const int ty   = threadIdx.x >> 6;
#pragma unroll
  for (int r = ty; r < 64; r += 4)
    t[r][lane] = in[(bb + r) * 12800 + kb + lane];
  __syncthreads();
#pragma unroll
  for (int r = ty; r < 64; r += 4)
    out[(kb + r) * 1024 + bb + lane] = t[lane][r];
}

// ---------------- conv2 (MFMA): c1t[12800][1024] -> c2t[5184][1024], k=4, s=2 -------------
__global__ __launch_bounds__(256, 1) void conv2_k(const __half* __restrict__ in,
                                                  const __half* __restrict__ w2h,
                                                  const float* __restrict__ bias,
                                                  __half* __restrict__ out) {
  __shared__ __align__(16) __half sh[2][9216];   // per buf: slab 8192 + W 1024 halves
  const int bid = blockIdx.x;          // 144 = 9 opy * 16 bt
  const int opy = bid % 9;
  const int bt  = bid / 9;
  const int bbase = bt * 64;
  const int tid  = threadIdx.x;
  const int lane = tid & 63;
  const int wv   = RL(tid >> 6);
  const int octile = wv & 1;
  const int bsub   = wv >> 1;
  const int kh = lane >> 5;
  const int ln = lane & 31;

  const unsigned short* inu = (const unsigned short*)in;
  const unsigned short* wu  = (const unsigned short*)w2h;

  int roff[5], offA[5];
#pragma unroll
  for (int p = 0; p < 5; ++p) {
    int idx = p * 256 + tid;
    int px = idx >> 6, b = idx & 63;
    roff[p] = px * 1024 + b;
    offA[p] = b * 128 + ((((px >> 1) ^ (b & 7)) << 3) | ((px & 1) << 2));
  }
  const int base0 = (40 * opy) * 1024 + bbase;

  f32x16 acc[9];
#pragma unroll
  for (int ox = 0; ox < 9; ++ox)
#pragma unroll
    for (int r = 0; r < 16; ++r) acc[ox][r] = 0.f;

  ushort4 s0, s1, s2, s3, s4; uint2 sW;

#define C2_LOAD(icv) do {                                                     \
    const unsigned short* ibp = inu + (icv) * 409600 + base0;                 \
    s0 = make_ushort4(ibp[roff[0]], ibp[roff[0]+20480], ibp[roff[0]+40960], ibp[roff[0]+61440]); \
    s1 = make_ushort4(ibp[roff[1]], ibp[roff[1]+20480], ibp[roff[1]+40960], ibp[roff[1]+61440]); \
    s2 = make_ushort4(ibp[roff[2]], ibp[roff[2]+20480], ibp[roff[2]+40960], ibp[roff[2]+61440]); \
    s3 = make_ushort4(ibp[roff[3]], ibp[roff[3]+20480], ibp[roff[3]+40960], ibp[roff[3]+61440]); \
    s4 = make_ushort4(ibp[roff[4]], ibp[roff[4]+20480], ibp[roff[4]+40960], ibp[roff[4]+61440]); \
    sW = *(const uint2*)(wu + (icv) * 1024 + tid * 4);                        \
  } while (0)

#define C2_STORE(buf) do {                                                    \
    *(uint2*)&sh[buf][offA[0]] = make_uint2((unsigned)s0.x | ((unsigned)s0.y << 16), (unsigned)s0.z | ((unsigned)s0.w << 16)); \
    *(uint2*)&sh[buf][offA[1]] = make_uint2((unsigned)s1.x | ((unsigned)s1.y << 16), (unsigned)s1.z | ((unsigned)s1.w << 16)); \
    *(uint2*)&sh[buf][offA[2]] = make_uint2((unsigned)s2.x | ((unsigned)s2.y << 16), (unsigned)s2.z | ((unsigned)s2.w << 16)); \
    *(uint2*)&sh[buf][offA[3]] = make_uint2((unsigned)s3.x | ((unsigned)s3.y << 16), (unsigned)s3.z | ((unsigned)s3.w << 16)); \
    *(uint2*)&sh[buf][offA[4]] = make_uint2((unsigned)s4.x | ((unsigned)s4.y << 16), (unsigned)s4.z | ((unsigned)s4.w << 16)); \
    *(uint2*)&sh[buf][8192 + tid * 4] = sW;                                   \
  } while (0)

  const int offW = 8192 + octile * 512 + kh * 256 + ln * 8;
  const int bloc = bsub * 32 + ln;
  const int bx7  = bloc & 7;
  const int brow = bloc * 128;

  int cur = 0;
  C2_LOAD(0);
#pragma unroll 1
  for (int ic = 0; ic < 32; ++ic) {
    __syncthreads();
    C2_STORE(cur);
    const int icn = ic < 31 ? ic + 1 : 31;
    C2_LOAD(icn);
    __syncthreads();
    f16x8 aw = *(const f16x8*)&sh[cur][offW];
#pragma unroll
    for (int ox = 0; ox < 9; ++ox) {
      f16x8 bx = *(const f16x8*)&sh[cur][brow + (((ox + kh) ^ bx7) << 3)];
      acc[ox] = __builtin_amdgcn_mfma_f32_32x32x16_f16(aw, bx, acc[ox], 0, 0, 0);
    }
    cur ^= 1;
  }
#undef C2_LOAD
#undef C2_STORE

  float bv[16];
#pragma unroll
  for (int r = 0; r < 16; ++r)
    bv[r] = bias[octile * 32 + (r & 3) + 8 * (r >> 2) + 4 * kh];
  const int bout = bbase + bloc;
#pragma unroll
  for (int ox = 0; ox < 9; ++ox) {
#pragma unroll
    for (int r = 0; r < 16; ++r) {
      const int oc = octile * 32 + (r & 3) + 8 * (r >> 2) + 4 * kh;
      float v = acc[ox][r] + bv[r];
      out[(oc * 81 + opy * 9 + ox) * 1024 + bout] = __float2half(v > 0.f ? v : 0.f);
    }
  }
}

// ---------------- conv3: c2t[5184][1024] -> c3t[3136][1024], k=3, s=1 (fp16 io) ----------
__global__ __launch_bounds__(128, 2) void conv3_k(const __half* __restrict__ in,
                                                  const float* __restrict__ wt,   // wt3n
                                                  const float* __restrict__ bias,
                                                  __half* __restrict__ out) {
  const int bid = blockIdx.x;            // 1792 = 128*(grp>>3) + 8*ocg + (grp&7)
  const int ocg = (bid >> 3) & 15;
  const int grp = ((bid >> 7) << 3) | (bid & 7);
  const int opy = grp % 7;
  const int bg  = grp / 7;
  const int tid  = threadIdx.x;
  const int lane = tid & 63;
  const int wv   = RL(tid >> 6);

  float acc[4][7];
#pragma unroll
  for (int o = 0; o < 4; ++o)
#pragma unroll
    for (int ox = 0; ox < 7; ++ox) acc[o][ox] = 0.f;

  const __half* ib = in + bg * 64 + lane;
  const int ic0 = wv * 32;

#pragma unroll 1
  for (int ici = 0; ici < 32; ++ici) {
    const int ic = ic0 + ici;
#pragma unroll
    for (int ky = 0; ky < 3; ++ky) {
      const float* wp = wt + ((ic * 3 + ky) * 8 + (ocg >> 1)) * 24 + (ocg & 1) * 12;
      float wk[12];
#pragma unroll
      for (int q = 0; q < 12; ++q) wk[q] = wp[q];
      const __half* rp = ib + (ic * 81 + (opy + ky) * 9) * 1024;
      float iv[9];
#pragma unroll
      for (int q = 0; q < 9; ++q) iv[q] = __half2float(rp[q * 1024]);
#pragma unroll
      for (int o = 0; o < 4; ++o)
#pragma unroll
        for (int ox = 0; ox < 7; ++ox)
#pragma unroll
          for (int kx = 0; kx < 3; ++kx)
            acc[o][ox] = fmaf(iv[ox + kx], wk[o * 3 + kx], acc[o][ox]);
    }
  }

  __shared__ float red[4][7][64];
  if (wv == 1) {
#pragma unroll
    for (int o = 0; o < 4; ++o)
#pragma unroll
      for (int ox = 0; ox < 7; ++ox) red[o][ox][lane] = acc[o][ox];
  }
  __syncthreads();
  if (wv == 0) {
#pragma unroll
    for (int o = 0; o < 4; ++o) {
      const int oc = ocg * 4 + o;
      const float bj = bias[oc];
#pragma unroll
      for (int ox = 0; ox < 7; ++ox) {
        float v = acc[o][ox] + red[o][ox][lane] + bj;
        out[(oc * 49 + opy * 7 + ox) * 1024 + bg * 64 + lane] =
            __float2half(v > 0.f ? v : 0.f);
      }
    }
  }
}

// ---------------- fc1a: c3t[3136][1024] @ fw1[3136][256] -> part[16][256][1024] -----------
__global__ __launch_bounds__(64, 2) void fc1a_k(const __half* __restrict__ a,
                                                const float* __restrict__ w,
                                                float* __restrict__ part) {
  const int bid = blockIdx.x;            // 4096 = 128*(grp>>3) + 8*jg + (grp&7)
  const int jg  = (bid >> 3) & 15;
  const int grp = ((bid >> 7) << 3) | (bid & 7);
  const int kc  = grp & 15;
  const int bg  = grp >> 4;
  const int lane = threadIdx.x;

  float acc[16];
#pragma unroll
  for (int j = 0; j < 16; ++j) acc[j] = 0.f;

  const __half* ap = a + kc * 196 * 1024 + bg * 64 + lane;
  const float* wp0 = w + kc * 196 * 256 + jg * 16;

#pragma unroll 4
  for (int k = 0; k < 196; ++k) {
    float av = __half2float(ap[k * 1024]);
    const float* wp = wp0 + k * 256;
#pragma unroll
    for (int j = 0; j < 16; ++j) acc[j] = fmaf(av, wp[j], acc[j]);
  }
#pragma unroll
  for (int j = 0; j < 16; ++j)
    part[(kc * 256 + jg * 16 + j) * 1024 + bg * 64 + lane] = acc[j];
}

// ---------------- fc1b: reduce 16 partials + bias + relu -> h_t[256][1024] ----------------
__global__ __launch_bounds__(256) void fc1b_k(const float* __restrict__ part,
                                              const float* __restrict__ bias,
                                              float* __restrict__ h) {
  int idx = blockIdx.x * 256 + threadIdx.x;   // j*1024 + b
  float s = bias[idx >> 10];
#pragma unroll
  for (int c = 0; c < 16; ++c) s += part[c * 262144 + idx];
  h[idx] = s > 0.f ? s : 0.f;
}

// ---------------- fc2 + softmax + dist/res (reads h_t[k][b]) ----------------
__global__ __launch_bounds__(256) void fc2_k(const float* __restrict__ h,     // [256][1024]
                                             const float* __restrict__ w,     // [256][51]
                                             const float* __restrict__ bias,
                                             const float* __restrict__ z,
                                             float* __restrict__ dist,        // [1024][6][51]
                                             float* __restrict__ res) {       // [1024][6]
  __shared__ float wl[256 * 51];
  const int tid = threadIdx.x;
#pragma unroll
  for (int i = tid; i < 256 * 51; i += 256) wl[i] = w[i];
  __syncthreads();

  const int j   = tid & 63;
  const int b   = blockIdx.x * 4 + RL(tid >> 6);
  const int jc = j < 51 ? j : 50;
  float acc = bias[jc];
#pragma unroll 8
  for (int k = 0; k < 256; ++k)
    acc = fmaf(h[k * 1024 + b], wl[k * 51 + jc], acc);
  float logit = (j < 51) ? acc : -1e30f;
  float m = logit;
#pragma unroll
  for (int o = 32; o > 0; o >>= 1) m = fmaxf(m, __shfl_xor(m, o, 64));
  float e = (j < 51) ? __expf(logit - m) : 0.f;
  float ssum = e;
#pragma unroll
  for (int o = 32; o > 0; o >>= 1) ssum += __shfl_xor(ssum, o, 64);
  float p = e / ssum;
  float zv = (j < 51) ? z[jc] : 0.f;
  float rz = p * zv;
#pragma unroll
  for (int o = 32; o > 0; o >>= 1) rz += __shfl_xor(rz, o, 64);
  if (j < 51) {
    float* db = dist + b * 6 * 51 + j;
#pragma unroll
    for (int n = 0; n < 6; ++n) db[n * 51] = p;
  }
  if (j < 6) res[b * 6 + j] = rz;
}

extern "C" void kernel_launch(void* const* d_in, const int* in_sizes, int n_in,
                              void* d_out, int out_size, void* d_ws, size_t ws_size,
                              hipStream_t stream) {
  const float* x   = (const float*)d_in[0];
  const float* cw1 = (const float*)d_in[1];
  const float* cb1 = (const float*)d_in[2];
  const float* cw2 = (const float*)d_in[3];
  const float* cb2 = (const float*)d_in[4];
  const float* cw3 = (const float*)d_in[5];
  const float* cb3 = (const float*)d_in[6];
  const float* fw1 = (const float*)d_in[7];
  const float* fb1 = (const float*)d_in[8];
  const float* fw2 = (const float*)d_in[9];
  const float* fb2 = (const float*)d_in[10];
  const float* z   = (const float*)d_in[11];

  float* ws = (float*)d_ws;
  // float-offsets (fp16 buffers occupy half):
  // c1h : [0, 6553600)          1024*12800 halfs (conv1 writes batch-major)
  // c1t : [6553600, 13107200)   12800*1024 halfs (t1 output)
  // c2t : [13107200, 15761408)  5184*1024 halfs
  // c3t : [15761408, 17367040)  3136*1024 halfs
  // part: [0, 4194304)          16*256*1024 fp32 (reuses dead c1h)
  // h_t : [4194304, 4456448)    256*1024 fp32
  __half* c1h = (__half*)ws;
  __half* c1t = (__half*)(ws + 6553600);
  __half* c2t = (__half*)(ws + 13107200);
  __half* c3t = (__half*)(ws + 15761408);
  float*  pw  = ws;
  float*  h_t = ws + 4194304;

  // Weight scratch in d_out (floats): wt3n [0,36864), w1h halves [36864,40960),
  // w2h halves [45056,61440). dist written last (fc2).
  float*  wt3n = (float*)d_out;
  __half* w1h  = (__half*)((float*)d_out + 36864);
  __half* w2h  = (__half*)((float*)d_out + 45056);

  float* dist = (float*)d_out;
  float* res  = dist + 1024 * 6 * 51;

  wprep_k<<<144, 256, 0, stream>>>(cw1, cw2, cw3, w1h, w2h, wt3n);
  conv1_k<<<1024, 256, 0, stream>>>(x, w1h, cb1, c1h);
  t1_k<<<dim3(200, 16), 256, 0, stream>>>(c1h, c1t);
  conv2_k<<<144, 256, 0, stream>>>(c1t, w2h, cb2, c2t);
  conv3_k<<<1792, 128, 0, stream>>>(c2t, wt3n, cb3, c3t);
  fc1a_k<<<4096, 64, 0, stream>>>(c3t, fw1, pw);
  fc1b_k<<<1024, 256, 0, stream>>>(pw, fb1, h_t);
  fc2_k<<<256, 256, 0, stream>>>(h_t, fw2, fb2, z, dist, res);
}

// Round 10
// 366.052 us; speedup vs baseline: 1.1919x; 1.0803x over previous
//
#include <hip/hip_runtime.h>
#include <hip/hip_fp16.h>

#define RL(x) __builtin_amdgcn_readfirstlane(x)

typedef _Float16 f16x8 __attribute__((ext_vector_type(8)));
typedef _Float16 f16x4 __attribute__((ext_vector_type(4)));
typedef float    f32x16 __attribute__((ext_vector_type(16)));

// ---------------- weight prep ----------------
// w1h fp16 A-frag order, PRE-SCALED by 1/256:
//   w1h[((ic*8+ky)*32 + oc)*8 + kx] = w1[oc*256 + ic*64 + ky*8 + kx] / 256      (8192 h)
// w2h fp16 MFMA-frag order: w2h[((ic*2+ot)*2+kh)*256 + ln*8 + j]
//      = w2[(ot*32+ln)*512 + ic*16 + ky*4 + kx],  k = kh*8+j, kx=k>>2, ky=k&3   (32768 h)
// w3h fp16 MFMA-frag order, ZERO-PADDED 3x3 -> 4x4 window (kx==3||ky==3 -> 0):
//   w3h[((ic*2+ot)*2+kh)*256 + ln*8 + j] = (kx<3&&ky<3) ? w3[(ot*32+ln)*576 + ic*9 + ky*3 + kx] : 0
//   with k = kh*8+j, kx=k>>2, ky=k&3                                            (65536 h)
__global__ __launch_bounds__(256) void wprep_k(const float* __restrict__ w1,
                                               const float* __restrict__ w2,
                                               const float* __restrict__ w3,
                                               __half* __restrict__ w1h,
                                               __half* __restrict__ w2h,
                                               __half* __restrict__ w3h) {
  int i = blockIdx.x * 256 + threadIdx.x;
  if (i < 8192) {
    int kx = i & 7, oc = (i >> 3) & 31, ky = (i >> 8) & 7, ic = i >> 11;
    w1h[i] = __float2half(w1[oc * 256 + ic * 64 + ky * 8 + kx] * 0.00390625f);
  }
  if (i < 32768) {
    int j = i & 7, ln = (i >> 3) & 31, kh = (i >> 8) & 1, ot = (i >> 9) & 1, ic = i >> 10;
    int k = kh * 8 + j, kx = k >> 2, ky = k & 3, oc = ot * 32 + ln;
    w2h[i] = __float2half(w2[oc * 512 + ic * 16 + ky * 4 + kx]);
  }
  if (i < 65536) {
    int j = i & 7, ln = (i >> 3) & 31, kh = (i >> 8) & 1, ot = (i >> 9) & 1, ic = i >> 10;
    int k = kh * 8 + j, kx = k >> 2, ky = k & 3, oc = ot * 32 + ln;
    float v = (kx < 3 && ky < 3) ? w3[oc * 576 + ic * 9 + ky * 3 + kx] : 0.f;
    w3h[i] = __float2half(v);
  }
}

// ---------------- conv1 (MFMA, pixels-on-lanes): x[1024,4,84,84] -> c1h[b][32*400] fp16 ---
__global__ __launch_bounds__(256, 2) void conv1_k(const float* __restrict__ x,
                                                  const __half* __restrict__ w1h,
                                                  const float* __restrict__ bias,
                                                  __half* __restrict__ out) {
  const int b = blockIdx.x;
  const int tid = threadIdx.x;
  const int lane = tid & 63;
  const int wv   = RL(tid >> 6);
  const int kh = lane >> 5;
  const int ln = lane & 31;
  const int nt = (wv == 0) ? 4 : 3;

  int ibs[4], pvv[4];
#pragma unroll
  for (int tt = 0; tt < 4; ++tt) {
    int p = (wv + tt * 4) * 32 + ln;
    pvv[tt] = (p < 400);
    if (p > 399) p = 399;
    int py = p / 20, px = p - py * 20;
    ibs[tt] = py * 336 + px * 4;
  }

  f32x16 acc[4];
#pragma unroll
  for (int tt = 0; tt < 4; ++tt)
#pragma unroll
    for (int r = 0; r < 16; ++r) acc[tt][r] = 0.f;

  const float* xb = x + b * 28224;

#pragma unroll 1
  for (int ic = 0; ic < 4; ++ic) {
#pragma unroll
    for (int t = 0; t < 4; ++t) {
      f16x8 aw = *(const f16x8*)(w1h + ((ic * 8 + 2 * t + kh) * 32 + ln) * 8);
      const float* rp = xb + ic * 7056 + (2 * t + kh) * 84;
#pragma unroll
      for (int tt = 0; tt < 4; ++tt) {
        if (tt < nt) {
          const float* ap = rp + ibs[tt];
          float4 lo = *(const float4*)ap;
          float4 hi = *(const float4*)(ap + 4);
          __half2 p0 = __floats2half2_rn(lo.x, lo.y);
          __half2 p1 = __floats2half2_rn(lo.z, lo.w);
          __half2 p2 = __floats2half2_rn(hi.x, hi.y);
          __half2 p3 = __floats2half2_rn(hi.z, hi.w);
          uint4 u = make_uint4(*(unsigned*)&p0, *(unsigned*)&p1,
                               *(unsigned*)&p2, *(unsigned*)&p3);
          f16x8 bx = *(f16x8*)&u;
          acc[tt] = __builtin_amdgcn_mfma_f32_32x32x16_f16(aw, bx, acc[tt], 0, 0, 0);
        }
      }
    }
  }

  float bv[16];
#pragma unroll
  for (int r = 0; r < 16; ++r)
    bv[r] = bias[(r & 3) + 8 * (r >> 2) + 4 * kh];

#pragma unroll
  for (int tt = 0; tt < 4; ++tt) {
    if (tt < nt && pvv[tt]) {
      const int p = (wv + tt * 4) * 32 + ln;
#pragma unroll
      for (int r = 0; r < 16; ++r) {
        const int oc = (r & 3) + 8 * (r >> 2) + 4 * kh;
        float v = acc[tt][r] + bv[r];
        out[b * 12800 + oc * 400 + p] = __float2half(v > 0.f ? v : 0.f);
      }
    }
  }
}

// ---------------- t1: transpose c1h[1024][12800] -> c1t[12800][1024] (fp16) ----------------
__global__ __launch_bounds__(256) void t1_k(const __half* __restrict__ in,
                                            __half* __restrict__ out) {
  __shared__ __half t[64][65];
  const int kb = blockIdx.x * 64;
  const int bb = blockIdx.y * 64;
  const int lane = threadIdx.x & 63;
  const int ty   = threadIdx.x >> 6;
#pragma unroll
  for (int r = ty; r < 64; r += 4)
    t[r][lane] = in[(bb + r) * 12800 + kb + lane];
  __syncthreads();
#pragma unroll
  for (int r = ty; r < 64; r += 4)
    out[(kb + r) * 1024 + bb + lane] = t[lane][r];
}

// ---------------- conv2 (MFMA): c1t[12800][1024] -> c2t[5184][1024], k=4, s=2 -------------
__global__ __launch_bounds__(256, 1) void conv2_k(const __half* __restrict__ in,
                                                  const __half* __restrict__ w2h,
                                                  const float* __restrict__ bias,
                                                  __half* __restrict__ out) {
  __shared__ __align__(16) __half sh[2][9216];   // per buf: slab 8192 + W 1024 halves
  const int bid = blockIdx.x;          // 144 = 9 opy * 16 bt
  const int opy = bid % 9;
  const int bt  = bid / 9;
  const int bbase = bt * 64;
  const int tid  = threadIdx.x;
  const int lane = tid & 63;
  const int wv   = RL(tid >> 6);
  const int octile = wv & 1;
  const int bsub   = wv >> 1;
  const int kh = lane >> 5;
  const int ln = lane & 31;

  const unsigned short* inu = (const unsigned short*)in;
  const unsigned short* wu  = (const unsigned short*)w2h;

  int roff[5], offA[5];
#pragma unroll
  for (int p = 0; p < 5; ++p) {
    int idx = p * 256 + tid;
    int px = idx >> 6, b = idx & 63;
    roff[p] = px * 1024 + b;
    offA[p] = b * 128 + ((((px >> 1) ^ (b & 7)) << 3) | ((px & 1) << 2));
  }
  const int base0 = (40 * opy) * 1024 + bbase;

  f32x16 acc[9];
#pragma unroll
  for (int ox = 0; ox < 9; ++ox)
#pragma unroll
    for (int r = 0; r < 16; ++r) acc[ox][r] = 0.f;

  ushort4 s0, s1, s2, s3, s4; uint2 sW;

#define C2_LOAD(icv) do {                                                     \
    const unsigned short* ibp = inu + (icv) * 409600 + base0;                 \
    s0 = make_ushort4(ibp[roff[0]], ibp[roff[0]+20480], ibp[roff[0]+40960], ibp[roff[0]+61440]); \
    s1 = make_ushort4(ibp[roff[1]], ibp[roff[1]+20480], ibp[roff[1]+40960], ibp[roff[1]+61440]); \
    s2 = make_ushort4(ibp[roff[2]], ibp[roff[2]+20480], ibp[roff[2]+40960], ibp[roff[2]+61440]); \
    s3 = make_ushort4(ibp[roff[3]], ibp[roff[3]+20480], ibp[roff[3]+40960], ibp[roff[3]+61440]); \
    s4 = make_ushort4(ibp[roff[4]], ibp[roff[4]+20480], ibp[roff[4]+40960], ibp[roff[4]+61440]); \
    sW = *(const uint2*)(wu + (icv) * 1024 + tid * 4);                        \
  } while (0)

#define C2_STORE(buf) do {                                                    \
    *(uint2*)&sh[buf][offA[0]] = make_uint2((unsigned)s0.x | ((unsigned)s0.y << 16), (unsigned)s0.z | ((unsigned)s0.w << 16)); \
    *(uint2*)&sh[buf][offA[1]] = make_uint2((unsigned)s1.x | ((unsigned)s1.y << 16), (unsigned)s1.z | ((unsigned)s1.w << 16)); \
    *(uint2*)&sh[buf][offA[2]] = make_uint2((unsigned)s2.x | ((unsigned)s2.y << 16), (unsigned)s2.z | ((unsigned)s2.w << 16)); \
    *(uint2*)&sh[buf][offA[3]] = make_uint2((unsigned)s3.x | ((unsigned)s3.y << 16), (unsigned)s3.z | ((unsigned)s3.w << 16)); \
    *(uint2*)&sh[buf][offA[4]] = make_uint2((unsigned)s4.x | ((unsigned)s4.y << 16), (unsigned)s4.z | ((unsigned)s4.w << 16)); \
    *(uint2*)&sh[buf][8192 + tid * 4] = sW;                                   \
  } while (0)

  const int offW = 8192 + octile * 512 + kh * 256 + ln * 8;
  const int bloc = bsub * 32 + ln;
  const int bx7  = bloc & 7;
  const int brow = bloc * 128;

  int cur = 0;
  C2_LOAD(0);
#pragma unroll 1
  for (int ic = 0; ic < 32; ++ic) {
    __syncthreads();
    C2_STORE(cur);
    const int icn = ic < 31 ? ic + 1 : 31;
    C2_LOAD(icn);
    __syncthreads();
    f16x8 aw = *(const f16x8*)&sh[cur][offW];
#pragma unroll
    for (int ox = 0; ox < 9; ++ox) {
      f16x8 bx = *(const f16x8*)&sh[cur][brow + (((ox + kh) ^ bx7) << 3)];
      acc[ox] = __builtin_amdgcn_mfma_f32_32x32x16_f16(aw, bx, acc[ox], 0, 0, 0);
    }
    cur ^= 1;
  }
#undef C2_LOAD
#undef C2_STORE

  float bv[16];
#pragma unroll
  for (int r = 0; r < 16; ++r)
    bv[r] = bias[octile * 32 + (r & 3) + 8 * (r >> 2) + 4 * kh];
  const int bout = bbase + bloc;
#pragma unroll
  for (int ox = 0; ox < 9; ++ox) {
#pragma unroll
    for (int r = 0; r < 16; ++r) {
      const int oc = octile * 32 + (r & 3) + 8 * (r >> 2) + 4 * kh;
      float v = acc[ox][r] + bv[r];
      out[(oc * 81 + opy * 9 + ox) * 1024 + bout] = __float2half(v > 0.f ? v : 0.f);
    }
  }
}

// ---------------- conv3 (MFMA): c2t[5184][1024] -> c3t[3136][1024], k=3, s=1 --------------
// Mirror of conv2's verified template. K=16 enumerates a 4x4 window (kx=k>>2, ky=k&3);
// weights zero-padded at kx==3||ky==3, input rows/cols clamped (only meet zero weights).
// Slab per ic: [b 64][px 10][ky 4] halves, b-stride 44 (8B-aligned ds_read_b64, ~2-way
// banks). B-frag = two b64 at b*44 + (ox+2kh)*4. Grid 112 = 7 opy * 16 bt.
__global__ __launch_bounds__(256, 1) void conv3_k(const __half* __restrict__ in,
                                                  const __half* __restrict__ w3h,
                                                  const float* __restrict__ bias,
                                                  __half* __restrict__ out) {
  __shared__ __align__(16) __half sh[2][3840];   // per buf: slab 2816 + W 1024 halves
  const int bid = blockIdx.x;          // 112 = 7 opy * 16 bt
  const int opy = bid % 7;
  const int bt  = bid / 7;
  const int bbase = bt * 64;
  const int tid  = threadIdx.x;
  const int lane = tid & 63;
  const int wv   = RL(tid >> 6);
  const int octile = wv & 1;
  const int bsub   = wv >> 1;
  const int kh = lane >> 5;
  const int ln = lane & 31;

  const unsigned short* inu = (const unsigned short*)in;
  const unsigned short* wu  = (const unsigned short*)w3h;

  int rof[4];
#pragma unroll
  for (int ky = 0; ky < 4; ++ky) {
    int r = opy + ky; if (r > 8) r = 8;          // clamped row -> zero weight
    rof[ky] = r * 9 * 1024;
  }
  // staging: idx = p*256+tid < 640: b = idx&63, px = idx>>6 (0..9, px=9 clamped)
  int gof[3], sof[3];
#pragma unroll
  for (int p = 0; p < 3; ++p) {
    int idx = p * 256 + tid;
    int b = idx & 63, px = idx >> 6;
    int pxc = px > 8 ? 8 : px;                   // clamped col -> zero weight
    gof[p] = pxc * 1024 + bbase + b;
    sof[p] = b * 44 + px * 4;
  }

  f32x16 acc[7];
#pragma unroll
  for (int ox = 0; ox < 7; ++ox)
#pragma unroll
    for (int r = 0; r < 16; ++r) acc[ox][r] = 0.f;

  ushort4 s0, s1, s2; uint2 sW;

#define C3_LOAD(icv) do {                                                     \
    const unsigned short* ibp = inu + (icv) * 82944;                          \
    s0 = make_ushort4(ibp[rof[0]+gof[0]], ibp[rof[1]+gof[0]],                 \
                      ibp[rof[2]+gof[0]], ibp[rof[3]+gof[0]]);                \
    s1 = make_ushort4(ibp[rof[0]+gof[1]], ibp[rof[1]+gof[1]],                 \
                      ibp[rof[2]+gof[1]], ibp[rof[3]+gof[1]]);                \
    if (tid < 128)                                                            \
      s2 = make_ushort4(ibp[rof[0]+gof[2]], ibp[rof[1]+gof[2]],               \
                        ibp[rof[2]+gof[2]], ibp[rof[3]+gof[2]]);              \
    sW = *(const uint2*)(wu + (icv) * 1024 + tid * 4);                        \
  } while (0)

#define C3_STORE(buf) do {                                                    \
    *(uint2*)&sh[buf][sof[0]] = make_uint2((unsigned)s0.x | ((unsigned)s0.y << 16), (unsigned)s0.z | ((unsigned)s0.w << 16)); \
    *(uint2*)&sh[buf][sof[1]] = make_uint2((unsigned)s1.x | ((unsigned)s1.y << 16), (unsigned)s1.z | ((unsigned)s1.w << 16)); \
    if (tid < 128)                                                            \
      *(uint2*)&sh[buf][sof[2]] = make_uint2((unsigned)s2.x | ((unsigned)s2.y << 16), (unsigned)s2.z | ((unsigned)s2.w << 16)); \
    *(uint2*)&sh[buf][2816 + tid * 4] = sW;                                   \
  } while (0)

  const int offW = 2816 + octile * 512 + kh * 256 + ln * 8;
  const int bloc = bsub * 32 + ln;
  const int brow = bloc * 44;

  int cur = 0;
  C3_LOAD(0);
#pragma unroll 1
  for (int ic = 0; ic < 64; ++ic) {
    __syncthreads();
    C3_STORE(cur);
    const int icn = ic < 63 ? ic + 1 : 63;
    C3_LOAD(icn);
    __syncthreads();
    f16x8 aw = *(const f16x8*)&sh[cur][offW];
#pragma unroll
    for (int ox = 0; ox < 7; ++ox) {
      const int p0 = ox + 2 * kh;
      f16x4 lo = *(const f16x4*)&sh[cur][brow + p0 * 4];
      f16x4 hi = *(const f16x4*)&sh[cur][brow + p0 * 4 + 4];
      f16x8 bx;
      bx[0]=lo[0]; bx[1]=lo[1]; bx[2]=lo[2]; bx[3]=lo[3];
      bx[4]=hi[0]; bx[5]=hi[1]; bx[6]=hi[2]; bx[7]=hi[3];
      acc[ox] = __builtin_amdgcn_mfma_f32_32x32x16_f16(aw, bx, acc[ox], 0, 0, 0);
    }
    cur ^= 1;
  }
#undef C3_LOAD
#undef C3_STORE

  float bv[16];
#pragma unroll
  for (int r = 0; r < 16; ++r)
    bv[r] = bias[octile * 32 + (r & 3) + 8 * (r >> 2) + 4 * kh];
  const int bout = bbase + bloc;
#pragma unroll
  for (int ox = 0; ox < 7; ++ox) {
#pragma unroll
    for (int r = 0; r < 16; ++r) {
      const int oc = octile * 32 + (r & 3) + 8 * (r >> 2) + 4 * kh;
      float v = acc[ox][r] + bv[r];
      out[(oc * 49 + opy * 7 + ox) * 1024 + bout] = __float2half(v > 0.f ? v : 0.f);
    }
  }
}

// ---------------- fc1a: c3t[3136][1024] @ fw1[3136][256] -> part[16][256][1024] -----------
__global__ __launch_bounds__(64, 2) void fc1a_k(const __half* __restrict__ a,
                                                const float* __restrict__ w,
                                                float* __restrict__ part) {
  const int bid = blockIdx.x;            // 4096 = 128*(grp>>3) + 8*jg + (grp&7)
  const int jg  = (bid >> 3) & 15;
  const int grp = ((bid >> 7) << 3) | (bid & 7);
  const int kc  = grp & 15;
  const int bg  = grp >> 4;
  const int lane = threadIdx.x;

  float acc[16];
#pragma unroll
  for (int j = 0; j < 16; ++j) acc[j] = 0.f;

  const __half* ap = a + kc * 196 * 1024 + bg * 64 + lane;
  const float* wp0 = w + kc * 196 * 256 + jg * 16;

#pragma unroll 4
  for (int k = 0; k < 196; ++k) {
    float av = __half2float(ap[k * 1024]);
    const float* wp = wp0 + k * 256;
#pragma unroll
    for (int j = 0; j < 16; ++j) acc[j] = fmaf(av, wp[j], acc[j]);
  }
#pragma unroll
  for (int j = 0; j < 16; ++j)
    part[(kc * 256 + jg * 16 + j) * 1024 + bg * 64 + lane] = acc[j];
}

// ---------------- fc1b: reduce 16 partials + bias + relu -> h_t[256][1024] ----------------
__global__ __launch_bounds__(256) void fc1b_k(const float* __restrict__ part,
                                              const float* __restrict__ bias,
                                              float* __restrict__ h) {
  int idx = blockIdx.x * 256 + threadIdx.x;   // j*1024 + b
  float s = bias[idx >> 10];
#pragma unroll
  for (int c = 0; c < 16; ++c) s += part[c * 262144 + idx];
  h[idx] = s > 0.f ? s : 0.f;
}

// ---------------- fc2 + softmax + dist/res (reads h_t[k][b]) ----------------
__global__ __launch_bounds__(256) void fc2_k(const float* __restrict__ h,     // [256][1024]
                                             const float* __restrict__ w,     // [256][51]
                                             const float* __restrict__ bias,
                                             const float* __restrict__ z,
                                             float* __restrict__ dist,        // [1024][6][51]
                                             float* __restrict__ res) {       // [1024][6]
  __shared__ float wl[256 * 51];
  const int tid = threadIdx.x;
#pragma unroll
  for (int i = tid; i < 256 * 51; i += 256) wl[i] = w[i];
  __syncthreads();

  const int j   = tid & 63;
  const int b   = blockIdx.x * 4 + RL(tid >> 6);
  const int jc = j < 51 ? j : 50;
  float acc = bias[jc];
#pragma unroll 8
  for (int k = 0; k < 256; ++k)
    acc = fmaf(h[k * 1024 + b], wl[k * 51 + jc], acc);
  float logit = (j < 51) ? acc : -1e30f;
  float m = logit;
#pragma unroll
  for (int o = 32; o > 0; o >>= 1) m = fmaxf(m, __shfl_xor(m, o, 64));
  float e = (j < 51) ? __expf(logit - m) : 0.f;
  float ssum = e;
#pragma unroll
  for (int o = 32; o > 0; o >>= 1) ssum += __shfl_xor(ssum, o, 64);
  float p = e / ssum;
  float zv = (j < 51) ? z[jc] : 0.f;
  float rz = p * zv;
#pragma unroll
  for (int o = 32; o > 0; o >>= 1) rz += __shfl_xor(rz, o, 64);
  if (j < 51) {
    float* db = dist + b * 6 * 51 + j;
#pragma unroll
    for (int n = 0; n < 6; ++n) db[n * 51] = p;
  }
  if (j < 6) res[b * 6 + j] = rz;
}

extern "C" void kernel_launch(void* const* d_in, const int* in_sizes, int n_in,
                              void* d_out, int out_size, void* d_ws, size_t ws_size,
                              hipStream_t stream) {
  const float* x   = (const float*)d_in[0];
  const float* cw1 = (const float*)d_in[1];
  const float* cb1 = (const float*)d_in[2];
  const float* cw2 = (const float*)d_in[3];
  const float* cb2 = (const float*)d_in[4];
  const float* cw3 = (const float*)d_in[5];
  const float* cb3 = (const float*)d_in[6];
  const float* fw1 = (const float*)d_in[7];
  const float* fb1 = (const float*)d_in[8];
  const float* fw2 = (const float*)d_in[9];
  const float* fb2 = (const float*)d_in[10];
  const float* z   = (const float*)d_in[11];

  float* ws = (float*)d_ws;
  // float-offsets (fp16 buffers occupy half):
  // c1h : [0, 6553600)          1024*12800 halfs (conv1 writes batch-major)
  // c1t : [6553600, 13107200)   12800*1024 halfs (t1 output)
  // c2t : [13107200, 15761408)  5184*1024 halfs
  // c3t : [15761408, 17367040)  3136*1024 halfs
  // part: [0, 4194304)          16*256*1024 fp32 (reuses dead c1h)
  // h_t : [4194304, 4456448)    256*1024 fp32
  __half* c1h = (__half*)ws;
  __half* c1t = (__half*)(ws + 6553600);
  __half* c2t = (__half*)(ws + 13107200);
  __half* c3t = (__half*)(ws + 15761408);
  float*  pw  = ws;
  float*  h_t = ws + 4194304;

  // Weight scratch in d_out (floats): w3h halves [0,65536) = floats [0,32768);
  // w1h halves at float-offset 36864; w2h halves at 45056. dist written last (fc2).
  __half* w3h  = (__half*)d_out;
  __half* w1h  = (__half*)((float*)d_out + 36864);
  __half* w2h  = (__half*)((float*)d_out + 45056);

  float* dist = (float*)d_out;
  float* res  = dist + 1024 * 6 * 51;

  wprep_k<<<256, 256, 0, stream>>>(cw1, cw2, cw3, w1h, w2h, w3h);
  conv1_k<<<1024, 256, 0, stream>>>(x, w1h, cb1, c1h);
  t1_k<<<dim3(200, 16), 256, 0, stream>>>(c1h, c1t);
  conv2_k<<<144, 256, 0, stream>>>(c1t, w2h, cb2, c2t);
  conv3_k<<<112, 256, 0, stream>>>(c2t, w3h, cb3, c3t);
  fc1a_k<<<4096, 64, 0, stream>>>(c3t, fw1, pw);
  fc1b_k<<<1024, 256, 0, stream>>>(pw, fb1, h_t);
  fc2_k<<<256, 256, 0, stream>>>(h_t, fw2, fb2, z, dist, res);
}

// Round 11
// 364.770 us; speedup vs baseline: 1.1961x; 1.0035x over previous
//
#include <hip/hip_runtime.h>
#include <hip/hip_fp16.h>

#define RL(x) __builtin_amdgcn_readfirstlane(x)

typedef _Float16 f16x8 __attribute__((ext_vector_type(8)));
typedef _Float16 f16x4 __attribute__((ext_vector_type(4)));
typedef float    f32x16 __attribute__((ext_vector_type(16)));

// ---------------- weight prep ----------------
// w1h fp16 A-frag order, PRE-SCALED by 1/256:
//   w1h[((ic*8+ky)*32 + oc)*8 + kx] = w1[oc*256 + ic*64 + ky*8 + kx] / 256      (8192 h)
// w2h fp16 MFMA-frag order: w2h[((ic*2+ot)*2+kh)*256 + ln*8 + j]
//      = w2[(ot*32+ln)*512 + ic*16 + ky*4 + kx],  k = kh*8+j, kx=k>>2, ky=k&3   (32768 h)
// w3h fp16 MFMA-frag order, ZERO-PADDED 3x3 -> 4x4 window (kx==3||ky==3 -> 0):
//   w3h[((ic*2+ot)*2+kh)*256 + ln*8 + j] = (kx<3&&ky<3) ? w3[(ot*32+ln)*576 + ic*9 + ky*3 + kx] : 0
//   with k = kh*8+j, kx=k>>2, ky=k&3                                            (65536 h)
__global__ __launch_bounds__(256) void wprep_k(const float* __restrict__ w1,
                                               const float* __restrict__ w2,
                                               const float* __restrict__ w3,
                                               __half* __restrict__ w1h,
                                               __half* __restrict__ w2h,
                                               __half* __restrict__ w3h) {
  int i = blockIdx.x * 256 + threadIdx.x;
  if (i < 8192) {
    int kx = i & 7, oc = (i >> 3) & 31, ky = (i >> 8) & 7, ic = i >> 11;
    w1h[i] = __float2half(w1[oc * 256 + ic * 64 + ky * 8 + kx] * 0.00390625f);
  }
  if (i < 32768) {
    int j = i & 7, ln = (i >> 3) & 31, kh = (i >> 8) & 1, ot = (i >> 9) & 1, ic = i >> 10;
    int k = kh * 8 + j, kx = k >> 2, ky = k & 3, oc = ot * 32 + ln;
    w2h[i] = __float2half(w2[oc * 512 + ic * 16 + ky * 4 + kx]);
  }
  if (i < 65536) {
    int j = i & 7, ln = (i >> 3) & 31, kh = (i >> 8) & 1, ot = (i >> 9) & 1, ic = i >> 10;
    int k = kh * 8 + j, kx = k >> 2, ky = k & 3, oc = ot * 32 + ln;
    float v = (kx < 3 && ky < 3) ? w3[oc * 576 + ic * 9 + ky * 3 + kx] : 0.f;
    w3h[i] = __float2half(v);
  }
}

// ---------------- conv1 (MFMA, pixels-on-lanes): x[1024,4,84,84] -> c1h[b][32*400] fp16 ---
// NEW: 2 blocks per image (pixel halves, grid 2048) -> 2x blocks/CU for TLP; all 16
// weight A-frags hoisted to registers up-front (kills per-phase dependent weight load);
// phase loop fully unrolled so x-loads schedule across phases.
__global__ __launch_bounds__(256, 2) void conv1_k(const float* __restrict__ x,
                                                  const __half* __restrict__ w1h,
                                                  const float* __restrict__ bias,
                                                  __half* __restrict__ out) {
  const int bid = blockIdx.x;        // 2048 = b*2 + ph
  const int ph  = bid & 1;
  const int b   = bid >> 1;
  const int tid = threadIdx.x;
  const int lane = tid & 63;
  const int wv   = RL(tid >> 6);
  const int kh = lane >> 5;
  const int ln = lane & 31;

  int ibs[2], pvv[2];
#pragma unroll
  for (int tt = 0; tt < 2; ++tt) {
    int pl = (wv + tt * 4) * 32 + ln;    // local pixel in this half (tiles wv, wv+4)
    pvv[tt] = (pl < 200);
    if (pl > 199) pl = 199;
    int p = ph * 200 + pl;
    int py = p / 20, px = p - py * 20;
    ibs[tt] = py * 336 + px * 4;
  }

  // hoist all 16 (ic,t) A-frags for this (kh,ln): 32 VGPRs, independent L2-hot loads
  f16x8 wreg[16];
#pragma unroll
  for (int f = 0; f < 16; ++f) {
    const int ic = f >> 2, t = f & 3;
    wreg[f] = *(const f16x8*)(w1h + ((ic * 8 + 2 * t + kh) * 32 + ln) * 8);
  }

  f32x16 acc[2];
#pragma unroll
  for (int tt = 0; tt < 2; ++tt)
#pragma unroll
    for (int r = 0; r < 16; ++r) acc[tt][r] = 0.f;

  const float* xb = x + b * 28224;

#pragma unroll
  for (int f = 0; f < 16; ++f) {
    const int ic = f >> 2, t = f & 3;
    const float* rp = xb + ic * 7056 + (2 * t + kh) * 84;
#pragma unroll
    for (int tt = 0; tt < 2; ++tt) {
      const float* ap = rp + ibs[tt];
      float4 lo = *(const float4*)ap;
      float4 hi = *(const float4*)(ap + 4);
      __half2 p0 = __floats2half2_rn(lo.x, lo.y);
      __half2 p1 = __floats2half2_rn(lo.z, lo.w);
      __half2 p2 = __floats2half2_rn(hi.x, hi.y);
      __half2 p3 = __floats2half2_rn(hi.z, hi.w);
      uint4 u = make_uint4(*(unsigned*)&p0, *(unsigned*)&p1,
                           *(unsigned*)&p2, *(unsigned*)&p3);
      f16x8 bx = *(f16x8*)&u;
      acc[tt] = __builtin_amdgcn_mfma_f32_32x32x16_f16(wreg[f], bx, acc[tt], 0, 0, 0);
    }
  }

  float bv[16];
#pragma unroll
  for (int r = 0; r < 16; ++r)
    bv[r] = bias[(r & 3) + 8 * (r >> 2) + 4 * kh];

#pragma unroll
  for (int tt = 0; tt < 2; ++tt) {
    if (pvv[tt]) {
      const int p = ph * 200 + (wv + tt * 4) * 32 + ln;
#pragma unroll
      for (int r = 0; r < 16; ++r) {
        const int oc = (r & 3) + 8 * (r >> 2) + 4 * kh;
        float v = acc[tt][r] + bv[r];
        out[b * 12800 + oc * 400 + p] = __float2half(v > 0.f ? v : 0.f);
      }
    }
  }
}

// ---------------- t1: transpose c1h[1024][12800] -> c1t[12800][1024] (fp16) ----------------
__global__ __launch_bounds__(256) void t1_k(const __half* __restrict__ in,
                                            __half* __restrict__ out) {
  __shared__ __half t[64][65];
  const int kb = blockIdx.x * 64;
  const int bb = blockIdx.y * 64;
  const int lane = threadIdx.x & 63;
  const int ty   = threadIdx.x >> 6;
#pragma unroll
  for (int r = ty; r < 64; r += 4)
    t[r][lane] = in[(bb + r) * 12800 + kb + lane];
  __syncthreads();
#pragma unroll
  for (int r = ty; r < 64; r += 4)
    out[(kb + r) * 1024 + bb + lane] = t[lane][r];
}

// ---------------- conv2 (MFMA): c1t[12800][1024] -> c2t[5184][1024], k=4, s=2 -------------
__global__ __launch_bounds__(256, 1) void conv2_k(const __half* __restrict__ in,
                                                  const __half* __restrict__ w2h,
                                                  const float* __restrict__ bias,
                                                  __half* __restrict__ out) {
  __shared__ __align__(16) __half sh[2][9216];   // per buf: slab 8192 + W 1024 halves
  const int bid = blockIdx.x;          // 144 = 9 opy * 16 bt
  const int opy = bid % 9;
  const int bt  = bid / 9;
  const int bbase = bt * 64;
  const int tid  = threadIdx.x;
  const int lane = tid & 63;
  const int wv   = RL(tid >> 6);
  const int octile = wv & 1;
  const int bsub   = wv >> 1;
  const int kh = lane >> 5;
  const int ln = lane & 31;

  const unsigned short* inu = (const unsigned short*)in;
  const unsigned short* wu  = (const unsigned short*)w2h;

  int roff[5], offA[5];
#pragma unroll
  for (int p = 0; p < 5; ++p) {
    int idx = p * 256 + tid;
    int px = idx >> 6, b = idx & 63;
    roff[p] = px * 1024 + b;
    offA[p] = b * 128 + ((((px >> 1) ^ (b & 7)) << 3) | ((px & 1) << 2));
  }
  const int base0 = (40 * opy) * 1024 + bbase;

  f32x16 acc[9];
#pragma unroll
  for (int ox = 0; ox < 9; ++ox)
#pragma unroll
    for (int r = 0; r < 16; ++r) acc[ox][r] = 0.f;

  ushort4 s0, s1, s2, s3, s4; uint2 sW;

#define C2_LOAD(icv) do {                                                     \
    const unsigned short* ibp = inu + (icv) * 409600 + base0;                 \
    s0 = make_ushort4(ibp[roff[0]], ibp[roff[0]+20480], ibp[roff[0]+40960], ibp[roff[0]+61440]); \
    s1 = make_ushort4(ibp[roff[1]], ibp[roff[1]+20480], ibp[roff[1]+40960], ibp[roff[1]+61440]); \
    s2 = make_ushort4(ibp[roff[2]], ibp[roff[2]+20480], ibp[roff[2]+40960], ibp[roff[2]+61440]); \
    s3 = make_ushort4(ibp[roff[3]], ibp[roff[3]+20480], ibp[roff[3]+40960], ibp[roff[3]+61440]); \
    s4 = make_ushort4(ibp[roff[4]], ibp[roff[4]+20480], ibp[roff[4]+40960], ibp[roff[4]+61440]); \
    sW = *(const uint2*)(wu + (icv) * 1024 + tid * 4);                        \
  } while (0)

#define C2_STORE(buf) do {                                                    \
    *(uint2*)&sh[buf][offA[0]] = make_uint2((unsigned)s0.x | ((unsigned)s0.y << 16), (unsigned)s0.z | ((unsigned)s0.w << 16)); \
    *(uint2*)&sh[buf][offA[1]] = make_uint2((unsigned)s1.x | ((unsigned)s1.y << 16), (unsigned)s1.z | ((unsigned)s1.w << 16)); \
    *(uint2*)&sh[buf][offA[2]] = make_uint2((unsigned)s2.x | ((unsigned)s2.y << 16), (unsigned)s2.z | ((unsigned)s2.w << 16)); \
    *(uint2*)&sh[buf][offA[3]] = make_uint2((unsigned)s3.x | ((unsigned)s3.y << 16), (unsigned)s3.z | ((unsigned)s3.w << 16)); \
    *(uint2*)&sh[buf][offA[4]] = make_uint2((unsigned)s4.x | ((unsigned)s4.y << 16), (unsigned)s4.z | ((unsigned)s4.w << 16)); \
    *(uint2*)&sh[buf][8192 + tid * 4] = sW;                                   \
  } while (0)

  const int offW = 8192 + octile * 512 + kh * 256 + ln * 8;
  const int bloc = bsub * 32 + ln;
  const int bx7  = bloc & 7;
  const int brow = bloc * 128;

  int cur = 0;
  C2_LOAD(0);
#pragma unroll 1
  for (int ic = 0; ic < 32; ++ic) {
    __syncthreads();
    C2_STORE(cur);
    const int icn = ic < 31 ? ic + 1 : 31;
    C2_LOAD(icn);
    __syncthreads();
    f16x8 aw = *(const f16x8*)&sh[cur][offW];
#pragma unroll
    for (int ox = 0; ox < 9; ++ox) {
      f16x8 bx = *(const f16x8*)&sh[cur][brow + (((ox + kh) ^ bx7) << 3)];
      acc[ox] = __builtin_amdgcn_mfma_f32_32x32x16_f16(aw, bx, acc[ox], 0, 0, 0);
    }
    cur ^= 1;
  }
#undef C2_LOAD
#undef C2_STORE

  float bv[16];
#pragma unroll
  for (int r = 0; r < 16; ++r)
    bv[r] = bias[octile * 32 + (r & 3) + 8 * (r >> 2) + 4 * kh];
  const int bout = bbase + bloc;
#pragma unroll
  for (int ox = 0; ox < 9; ++ox) {
#pragma unroll
    for (int r = 0; r < 16; ++r) {
      const int oc = octile * 32 + (r & 3) + 8 * (r >> 2) + 4 * kh;
      float v = acc[ox][r] + bv[r];
      out[(oc * 81 + opy * 9 + ox) * 1024 + bout] = __float2half(v > 0.f ? v : 0.f);
    }
  }
}

// ---------------- conv3 (MFMA): c2t[5184][1024] -> c3t[3136][1024], k=3, s=1 --------------
__global__ __launch_bounds__(256, 1) void conv3_k(const __half* __restrict__ in,
                                                  const __half* __restrict__ w3h,
                                                  const float* __restrict__ bias,
                                                  __half* __restrict__ out) {
  __shared__ __align__(16) __half sh[2][3840];   // per buf: slab 2816 + W 1024 halves
  const int bid = blockIdx.x;          // 112 = 7 opy * 16 bt
  const int opy = bid % 7;
  const int bt  = bid / 7;
  const int bbase = bt * 64;
  const int tid  = threadIdx.x;
  const int lane = tid & 63;
  const int wv   = RL(tid >> 6);
  const int octile = wv & 1;
  const int bsub   = wv >> 1;
  const int kh = lane >> 5;
  const int ln = lane & 31;

  const unsigned short* inu = (const unsigned short*)in;
  const unsigned short* wu  = (const unsigned short*)w3h;

  int rof[4];
#pragma unroll
  for (int ky = 0; ky < 4; ++ky) {
    int r = opy + ky; if (r > 8) r = 8;          // clamped row -> zero weight
    rof[ky] = r * 9 * 1024;
  }
  int gof[3], sof[3];
#pragma unroll
  for (int p = 0; p < 3; ++p) {
    int idx = p * 256 + tid;
    int b = idx & 63, px = idx >> 6;
    int pxc = px > 8 ? 8 : px;                   // clamped col -> zero weight
    gof[p] = pxc * 1024 + bbase + b;
    sof[p] = b * 44 + px * 4;
  }

  f32x16 acc[7];
#pragma unroll
  for (int ox = 0; ox < 7; ++ox)
#pragma unroll
    for (int r = 0; r < 16; ++r) acc[ox][r] = 0.f;

  ushort4 s0, s1, s2; uint2 sW;

#define C3_LOAD(icv) do {                                                     \
    const unsigned short* ibp = inu + (icv) * 82944;                          \
    s0 = make_ushort4(ibp[rof[0]+gof[0]], ibp[rof[1]+gof[0]],                 \
                      ibp[rof[2]+gof[0]], ibp[rof[3]+gof[0]]);                \
    s1 = make_ushort4(ibp[rof[0]+gof[1]], ibp[rof[1]+gof[1]],                 \
                      ibp[rof[2]+gof[1]], ibp[rof[3]+gof[1]]);                \
    if (tid < 128)                                                            \
      s2 = make_ushort4(ibp[rof[0]+gof[2]], ibp[rof[1]+gof[2]],               \
                        ibp[rof[2]+gof[2]], ibp[rof[3]+gof[2]]);              \
    sW = *(const uint2*)(wu + (icv) * 1024 + tid * 4);                        \
  } while (0)

#define C3_STORE(buf) do {                                                    \
    *(uint2*)&sh[buf][sof[0]] = make_uint2((unsigned)s0.x | ((unsigned)s0.y << 16), (unsigned)s0.z | ((unsigned)s0.w << 16)); \
    *(uint2*)&sh[buf][sof[1]] = make_uint2((unsigned)s1.x | ((unsigned)s1.y << 16), (unsigned)s1.z | ((unsigned)s1.w << 16)); \
    if (tid < 128)                                                            \
      *(uint2*)&sh[buf][sof[2]] = make_uint2((unsigned)s2.x | ((unsigned)s2.y << 16), (unsigned)s2.z | ((unsigned)s2.w << 16)); \
    *(uint2*)&sh[buf][2816 + tid * 4] = sW;                                   \
  } while (0)

  const int offW = 2816 + octile * 512 + kh * 256 + ln * 8;
  const int bloc = bsub * 32 + ln;
  const int brow = bloc * 44;

  int cur = 0;
  C3_LOAD(0);
#pragma unroll 1
  for (int ic = 0; ic < 64; ++ic) {
    __syncthreads();
    C3_STORE(cur);
    const int icn = ic < 63 ? ic + 1 : 63;
    C3_LOAD(icn);
    __syncthreads();
    f16x8 aw = *(const f16x8*)&sh[cur][offW];
#pragma unroll
    for (int ox = 0; ox < 7; ++ox) {
      const int p0 = ox + 2 * kh;
      f16x4 lo = *(const f16x4*)&sh[cur][brow + p0 * 4];
      f16x4 hi = *(const f16x4*)&sh[cur][brow + p0 * 4 + 4];
      f16x8 bx;
      bx[0]=lo[0]; bx[1]=lo[1]; bx[2]=lo[2]; bx[3]=lo[3];
      bx[4]=hi[0]; bx[5]=hi[1]; bx[6]=hi[2]; bx[7]=hi[3];
      acc[ox] = __builtin_amdgcn_mfma_f32_32x32x16_f16(aw, bx, acc[ox], 0, 0, 0);
    }
    cur ^= 1;
  }
#undef C3_LOAD
#undef C3_STORE

  float bv[16];
#pragma unroll
  for (int r = 0; r < 16; ++r)
    bv[r] = bias[octile * 32 + (r & 3) + 8 * (r >> 2) + 4 * kh];
  const int bout = bbase + bloc;
#pragma unroll
  for (int ox = 0; ox < 7; ++ox) {
#pragma unroll
    for (int r = 0; r < 16; ++r) {
      const int oc = octile * 32 + (r & 3) + 8 * (r >> 2) + 4 * kh;
      float v = acc[ox][r] + bv[r];
      out[(oc * 49 + opy * 7 + ox) * 1024 + bout] = __float2half(v > 0.f ? v : 0.f);
    }
  }
}

// ---------------- fc1a: c3t[3136][1024] @ fw1[3136][256] -> part[16][256][1024] -----------
__global__ __launch_bounds__(64, 2) void fc1a_k(const __half* __restrict__ a,
                                                const float* __restrict__ w,
                                                float* __restrict__ part) {
  const int bid = blockIdx.x;            // 4096 = 128*(grp>>3) + 8*jg + (grp&7)
  const int jg  = (bid >> 3) & 15;
  const int grp = ((bid >> 7) << 3) | (bid & 7);
  const int kc  = grp & 15;
  const int bg  = grp >> 4;
  const int lane = threadIdx.x;

  float acc[16];
#pragma unroll
  for (int j = 0; j < 16; ++j) acc[j] = 0.f;

  const __half* ap = a + kc * 196 * 1024 + bg * 64 + lane;
  const float* wp0 = w + kc * 196 * 256 + jg * 16;

#pragma unroll 4
  for (int k = 0; k < 196; ++k) {
    float av = __half2float(ap[k * 1024]);
    const float* wp = wp0 + k * 256;
#pragma unroll
    for (int j = 0; j < 16; ++j) acc[j] = fmaf(av, wp[j], acc[j]);
  }
#pragma unroll
  for (int j = 0; j < 16; ++j)
    part[(kc * 256 + jg * 16 + j) * 1024 + bg * 64 + lane] = acc[j];
}

// ---------------- fc1b: reduce 16 partials + bias + relu -> h_t[256][1024] ----------------
__global__ __launch_bounds__(256) void fc1b_k(const float* __restrict__ part,
                                              const float* __restrict__ bias,
                                              float* __restrict__ h) {
  int idx = blockIdx.x * 256 + threadIdx.x;   // j*1024 + b
  float s = bias[idx >> 10];
#pragma unroll
  for (int c = 0; c < 16; ++c) s += part[c * 262144 + idx];
  h[idx] = s > 0.f ? s : 0.f;
}

// ---------------- fc2 + softmax + dist/res (reads h_t[k][b]) ----------------
__global__ __launch_bounds__(256) void fc2_k(const float* __restrict__ h,     // [256][1024]
                                             const float* __restrict__ w,     // [256][51]
                                             const float* __restrict__ bias,
                                             const float* __restrict__ z,
                                             float* __restrict__ dist,        // [1024][6][51]
                                             float* __restrict__ res) {       // [1024][6]
  __shared__ float wl[256 * 51];
  const int tid = threadIdx.x;
#pragma unroll
  for (int i = tid; i < 256 * 51; i += 256) wl[i] = w[i];
  __syncthreads();

  const int j   = tid & 63;
  const int b   = blockIdx.x * 4 + RL(tid >> 6);
  const int jc = j < 51 ? j : 50;
  float acc = bias[jc];
#pragma unroll 8
  for (int k = 0; k < 256; ++k)
    acc = fmaf(h[k * 1024 + b], wl[k * 51 + jc], acc);
  float logit = (j < 51) ? acc : -1e30f;
  float m = logit;
#pragma unroll
  for (int o = 32; o > 0; o >>= 1) m = fmaxf(m, __shfl_xor(m, o, 64));
  float e = (j < 51) ? __expf(logit - m) : 0.f;
  float ssum = e;
#pragma unroll
  for (int o = 32; o > 0; o >>= 1) ssum += __shfl_xor(ssum, o, 64);
  float p = e / ssum;
  float zv = (j < 51) ? z[jc] : 0.f;
  float rz = p * zv;
#pragma unroll
  for (int o = 32; o > 0; o >>= 1) rz += __shfl_xor(rz, o, 64);
  if (j < 51) {
    float* db = dist + b * 6 * 51 + j;
#pragma unroll
    for (int n = 0; n < 6; ++n) db[n * 51] = p;
  }
  if (j < 6) res[b * 6 + j] = rz;
}

extern "C" void kernel_launch(void* const* d_in, const int* in_sizes, int n_in,
                              void* d_out, int out_size, void* d_ws, size_t ws_size,
                              hipStream_t stream) {
  const float* x   = (const float*)d_in[0];
  const float* cw1 = (const float*)d_in[1];
  const float* cb1 = (const float*)d_in[2];
  const float* cw2 = (const float*)d_in[3];
  const float* cb2 = (const float*)d_in[4];
  const float* cw3 = (const float*)d_in[5];
  const float* cb3 = (const float*)d_in[6];
  const float* fw1 = (const float*)d_in[7];
  const float* fb1 = (const float*)d_in[8];
  const float* fw2 = (const float*)d_in[9];
  const float* fb2 = (const float*)d_in[10];
  const float* z   = (const float*)d_in[11];

  float* ws = (float*)d_ws;
  // float-offsets (fp16 buffers occupy half):
  // c1h : [0, 6553600)          1024*12800 halfs (conv1 writes batch-major)
  // c1t : [6553600, 13107200)   12800*1024 halfs (t1 output)
  // c2t : [13107200, 15761408)  5184*1024 halfs
  // c3t : [15761408, 17367040)  3136*1024 halfs
  // part: [0, 4194304)          16*256*1024 fp32 (reuses dead c1h)
  // h_t : [4194304, 4456448)    256*1024 fp32
  __half* c1h = (__half*)ws;
  __half* c1t = (__half*)(ws + 6553600);
  __half* c2t = (__half*)(ws + 13107200);
  __half* c3t = (__half*)(ws + 15761408);
  float*  pw  = ws;
  float*  h_t = ws + 4194304;

  // Weight scratch in d_out (floats): w3h halves [0,65536) = floats [0,32768);
  // w1h halves at float-offset 36864; w2h halves at 45056. dist written last (fc2).
  __half* w3h  = (__half*)d_out;
  __half* w1h  = (__half*)((float*)d_out + 36864);
  __half* w2h  = (__half*)((float*)d_out + 45056);

  float* dist = (float*)d_out;
  float* res  = dist + 1024 * 6 * 51;

  wprep_k<<<256, 256, 0, stream>>>(cw1, cw2, cw3, w1h, w2h, w3h);
  conv1_k<<<2048, 256, 0, stream>>>(x, w1h, cb1, c1h);
  t1_k<<<dim3(200, 16), 256, 0, stream>>>(c1h, c1t);
  conv2_k<<<144, 256, 0, stream>>>(c1t, w2h, cb2, c2t);
  conv3_k<<<112, 256, 0, stream>>>(c2t, w3h, cb3, c3t);
  fc1a_k<<<4096, 64, 0, stream>>>(c3t, fw1, pw);
  fc1b_k<<<1024, 256, 0, stream>>>(pw, fb1, h_t);
  fc2_k<<<256, 256, 0, stream>>>(h_t, fw2, fb2, z, dist, res);
}